// Round 1
// 820.127 us; speedup vs baseline: 1.0787x; 1.0787x over previous
//
#include <hip/hip_runtime.h>
#include <hip/hip_bf16.h>

#define HW 65536
#define BATCH 4
#define NPIX (BATCH*HW)   // 262144 pixels

typedef unsigned short u16;
typedef unsigned int   u32;
typedef __attribute__((ext_vector_type(8))) short bh8;   // 8 bf16 (A/B frag, 4 VGPRs)
typedef __attribute__((ext_vector_type(4))) float f4;    // 4 f32 (C/D frag)

__device__ __forceinline__ float b2f(u16 u){
    u32 i = ((u32)u) << 16; float f; __builtin_memcpy(&f, &i, 4); return f;
}
__device__ __forceinline__ u16 f2b(float f){
    __hip_bfloat16 h = __float2bfloat16(f); u16 u; __builtin_memcpy(&u, &h, 2); return u;
}

__device__ __forceinline__ f4 mfma16(bh8 a, bh8 b, f4 c){
    return __builtin_amdgcn_mfma_f32_16x16x32_bf16(a, b, c, 0, 0, 0);
}

// ---------------- weight conversion (f32 -> bf16 arena) ----------------
struct CvtJob { const float* src; u16* dst; int n; };
struct CvtJobs { CvtJob j[12]; };
__global__ void cvt_kernel(CvtJobs jobs){
    const CvtJob J = jobs.j[blockIdx.x];
    for (int i = threadIdx.x; i < J.n; i += 256) J.dst[i] = f2b(J.src[i]);
}
__global__ void zero_kernel(float* p, int n){
    int i = blockIdx.x*256 + threadIdx.x;
    if (i < n) p[i] = 0.f;
}

// ---------------- LayerNorm, 2 px/thread (f32 in -> bf16 out) ----------------
__global__ __launch_bounds__(256) void ln2_kernel(const float* __restrict__ x,
                                                  const float* __restrict__ w,
                                                  const float* __restrict__ bs,
                                                  u16* __restrict__ out){
    int gid = blockIdx.x*256 + threadIdx.x;          // NPIX/2 groups
    int b = gid >> 15;                               // 32768 groups per batch
    int p = (gid & 32767) << 1;
    const float* px = x + (size_t)b*64*HW + p;
    u16* po = out + (size_t)b*64*HW + p;
    float v0[64], v1[64]; float mu0 = 0.f, mu1 = 0.f;
    #pragma unroll
    for (int c = 0; c < 64; c++){
        float2 f = *(const float2*)(px + (size_t)c*HW);
        v0[c] = f.x; v1[c] = f.y; mu0 += f.x; mu1 += f.y;
    }
    mu0 *= (1.f/64.f); mu1 *= (1.f/64.f);
    float va0 = 0.f, va1 = 0.f;
    #pragma unroll
    for (int c = 0; c < 64; c++){
        float d0 = v0[c]-mu0, d1 = v1[c]-mu1; va0 = fmaf(d0,d0,va0); va1 = fmaf(d1,d1,va1);
    }
    float i0 = rsqrtf(va0*(1.f/64.f) + 1e-5f);
    float i1 = rsqrtf(va1*(1.f/64.f) + 1e-5f);
    #pragma unroll
    for (int c = 0; c < 64; c++){
        u32 pk = (u32)f2b((v0[c]-mu0)*i0*w[c] + bs[c])
               | ((u32)f2b((v1[c]-mu1)*i1*w[c] + bs[c]) << 16);
        *(u32*)(po + (size_t)c*HW) = pk;
    }
}

// ---------------- MFMA GEMM over pixels ----------------
// M = MT*16 out-channels, K = KT*32 in-channels. Input planes are [B][64][HW]
// (inHi used for k>=64). Weights WA: bf16 [M][KD] row-major, KD = DIAG2?64:K.
// N-mapping: each lane owns the adjacent pixel pair {pbase, pbase+1}
// (frag 0 = even px, frag 1 = odd px) so B-loads are one u32 (bf16 pair) /
// float2 (f32 pair) and epilogue stores are packed u32 / float2.
// EPI: 0 = store bf16 planes, 1 = +bias+lrelu, 2 = vmod (v = v*(s+1)+t on vP),
//      3 = final (+f32 resid, f32 store, per-batch Weff A-matrix)
template<int MT, int KT, bool DIAG2, int EPI, typename TB>
__global__ __launch_bounds__(256) void gemm_kernel(
        const TB* __restrict__ inLo, const TB* __restrict__ inHi,
        const u16* __restrict__ WA,
        const float* __restrict__ bias_lo, const float* __restrict__ bias_hi,
        u16* __restrict__ outLo, u16* __restrict__ outHi,
        u16* __restrict__ vP,
        const float* __restrict__ resid, float* __restrict__ outF){
    constexpr int KD = DIAG2 ? (KT/2)*32 : KT*32;   // arena row stride
    constexpr int KA = DIAG2 ? KT/2 : KT;           // stored k-steps per row
    int tile = blockIdx.x;                          // NPIX/128 tiles
    int w = threadIdx.x >> 6, lane = threadIdx.x & 63;
    int quad = lane >> 4, l16 = lane & 15;
    int b = tile >> 9;                              // 512 tiles per batch
    int pbase = ((tile & 511) << 7) + (w << 5) + (l16 << 1);  // even pixel

    // A fragments from the bf16 weight arena (contiguous 16B per frag)
    bh8 a[MT][KA];
    const u16* wbase = (EPI == 3) ? (WA + b*4096) : WA;
    #pragma unroll
    for (int mi = 0; mi < MT; mi++){
        int row = mi*16 + l16;
        #pragma unroll
        for (int ks = 0; ks < KA; ks++)
            __builtin_memcpy(&a[mi][ks], wbase + row*KD + ks*32 + quad*8, 16);
    }
    f4 acc[MT][2];
    #pragma unroll
    for (int mi = 0; mi < MT; mi++){ acc[mi][0] = (f4){0.f,0.f,0.f,0.f}; acc[mi][1] = (f4){0.f,0.f,0.f,0.f}; }

    #pragma unroll
    for (int ks = 0; ks < KT; ks++){
        int kblk = ks*32 + quad*8;
        const TB* base = (kblk < 64) ? inLo : inHi;
        const TB* pp = base + ((size_t)b*64 + (kblk & 63))*HW + pbase;
        bh8 b0, b1;
        #pragma unroll
        for (int j = 0; j < 8; j++){
            if constexpr (sizeof(TB) == 2){
                u32 m = *(const u32*)(pp + (size_t)j*HW);
                b0[j] = (short)(m & 0xffffu);
                b1[j] = (short)(m >> 16);
            } else {
                float2 f = *(const float2*)(pp + (size_t)j*HW);
                b0[j] = (short)f2b(f.x);
                b1[j] = (short)f2b(f.y);
            }
        }
        #pragma unroll
        for (int mi = 0; mi < MT; mi++){
            if (!DIAG2 || (mi < MT/2 ? (ks < KT/2) : (ks >= KT/2))){
                int ksl = (DIAG2 && mi >= MT/2) ? ks - KT/2 : ks;
                acc[mi][0] = mfma16(a[mi][ksl], b0, acc[mi][0]);
                acc[mi][1] = mfma16(a[mi][ksl], b1, acc[mi][1]);
            }
        }
    }

    if constexpr (EPI == 2){
        // rows 0..63 = s (+bias_lo), rows 64..127 = t (+bias_hi); v' = v*(s+1)+t
        #pragma unroll
        for (int mi = 0; mi < MT/2; mi++)
        #pragma unroll
        for (int r = 0; r < 4; r++){
            int o = mi*16 + quad*4 + r;
            size_t pidx = ((size_t)b*64 + o)*HW + pbase;
            float s0 = acc[mi][0][r] + bias_lo[o];
            float s1 = acc[mi][1][r] + bias_lo[o];
            float t0 = acc[mi+MT/2][0][r] + bias_hi[o];
            float t1 = acc[mi+MT/2][1][r] + bias_hi[o];
            u32 vv = *(u32*)(vP + pidx);
            float v0 = b2f((u16)(vv & 0xffffu)), v1 = b2f((u16)(vv >> 16));
            *(u32*)(vP + pidx) = (u32)f2b(v0*(s0+1.f)+t0)
                               | ((u32)f2b(v1*(s1+1.f)+t1) << 16);
        }
    } else {
        #pragma unroll
        for (int mi = 0; mi < MT; mi++)
        #pragma unroll
        for (int r = 0; r < 4; r++){
            int o = mi*16 + quad*4 + r;
            size_t pidx = ((size_t)b*64 + (o & 63))*HW + pbase;
            float va0 = acc[mi][0][r];
            float va1 = acc[mi][1][r];
            if constexpr (EPI == 3){
                float2 rr = *(const float2*)(resid + pidx);
                float2 st; st.x = va0 + rr.x; st.y = va1 + rr.y;
                *(float2*)(outF + pidx) = st;
            } else {
                if constexpr (EPI == 1){
                    float bi = (o < 64) ? bias_lo[o] : bias_hi[o-64];
                    va0 += bi; va1 += bi;
                    va0 = va0 > 0.f ? va0 : 0.1f*va0;
                    va1 = va1 > 0.f ? va1 : 0.1f*va1;
                }
                u16* dst = (o < 64) ? outLo : outHi;
                *(u32*)(dst + pidx) = (u32)f2b(va0) | ((u32)f2b(va1) << 16);
            }
        }
    }
}

// ---------------- depthwise 3x3, 8 px/thread, vectorized ----------------
__global__ __launch_bounds__(256) void dw8_kernel(const u16* __restrict__ in,
                                                  const float* __restrict__ wdw, int choff,
                                                  u16* __restrict__ out){
    int gid = blockIdx.x*256 + threadIdx.x;     // B*64*8192 groups
    int bc = gid >> 13;
    int n8 = gid & 8191;
    int h = n8 >> 5, c8 = (n8 & 31) << 3;
    const float* wc = wdw + ((size_t)((bc & 63) + choff))*9;
    const u16* p = in + (size_t)bc*HW;
    float row[3][10];
    #pragma unroll
    for (int r = 0; r < 3; r++){
        int hh = h - 1 + r;
        bool ok = (unsigned)hh < 256u;
        const u16* pr = p + hh*256 + c8;
        if (ok){
            uint4 m = *(const uint4*)pr;          // 8 bf16
            row[r][1] = b2f((u16)m.x); row[r][2] = b2f((u16)(m.x>>16));
            row[r][3] = b2f((u16)m.y); row[r][4] = b2f((u16)(m.y>>16));
            row[r][5] = b2f((u16)m.z); row[r][6] = b2f((u16)(m.z>>16));
            row[r][7] = b2f((u16)m.w); row[r][8] = b2f((u16)(m.w>>16));
            row[r][0] = (c8 > 0)   ? b2f(pr[-1]) : 0.f;
            row[r][9] = (c8 < 248) ? b2f(pr[8])  : 0.f;
        } else {
            #pragma unroll
            for (int j = 0; j < 10; j++) row[r][j] = 0.f;
        }
    }
    float o[8];
    #pragma unroll
    for (int i = 0; i < 8; i++){
        float a = 0.f;
        #pragma unroll
        for (int r = 0; r < 3; r++){
            a = fmaf(wc[r*3+0], row[r][i],   a);
            a = fmaf(wc[r*3+1], row[r][i+1], a);
            a = fmaf(wc[r*3+2], row[r][i+2], a);
        }
        o[i] = a;
    }
    uint4 st;
    st.x = (u32)f2b(o[0]) | ((u32)f2b(o[1])<<16);
    st.y = (u32)f2b(o[2]) | ((u32)f2b(o[3])<<16);
    st.z = (u32)f2b(o[4]) | ((u32)f2b(o[5])<<16);
    st.w = (u32)f2b(o[6]) | ((u32)f2b(o[7])<<16);
    *(uint4*)(out + (size_t)bc*HW + h*256 + c8) = st;
}

// ---------------- attention partial sums (Gram + norms), atomic ----------------
// uint2 loads: 4 consecutive pixels per thread, exactly one pass per slice.
#define NSL 64
__global__ __launch_bounds__(256) void attn_part_kernel(const u16* __restrict__ q,
                                                        const u16* __restrict__ k,
                                                        float* __restrict__ sums){
    int blk = blockIdx.x;            // B*8*NSL
    int sl = blk & (NSL-1);
    int bh = blk >> 6;               // b*8+h
    int b = bh >> 3, h = bh & 7;
    const u16* qp = q + ((size_t)b*64 + h*8)*HW + sl*(HW/NSL);
    const u16* kp = k + ((size_t)b*64 + h*8)*HW + sl*(HW/NSL);
    float acc[80];
    #pragma unroll
    for (int i = 0; i < 80; i++) acc[i] = 0.f;
    int n0 = threadIdx.x << 2;       // 256 threads * 4 px = 1024 = HW/NSL
    float qv[8][4], kw[8][4];
    #pragma unroll
    for (int i = 0; i < 8; i++){
        uint2 mq = *(const uint2*)(qp + (size_t)i*HW + n0);
        uint2 mk = *(const uint2*)(kp + (size_t)i*HW + n0);
        qv[i][0] = b2f((u16)(mq.x & 0xffffu)); qv[i][1] = b2f((u16)(mq.x >> 16));
        qv[i][2] = b2f((u16)(mq.y & 0xffffu)); qv[i][3] = b2f((u16)(mq.y >> 16));
        kw[i][0] = b2f((u16)(mk.x & 0xffffu)); kw[i][1] = b2f((u16)(mk.x >> 16));
        kw[i][2] = b2f((u16)(mk.y & 0xffffu)); kw[i][3] = b2f((u16)(mk.y >> 16));
    }
    #pragma unroll
    for (int i = 0; i < 8; i++){
        #pragma unroll
        for (int u = 0; u < 4; u++){
            acc[64+i] = fmaf(qv[i][u], qv[i][u], acc[64+i]);
            acc[72+i] = fmaf(kw[i][u], kw[i][u], acc[72+i]);
        }
        #pragma unroll
        for (int j = 0; j < 8; j++)
            #pragma unroll
            for (int u = 0; u < 4; u++)
                acc[i*8+j] = fmaf(qv[i][u], kw[j][u], acc[i*8+j]);
    }
    __shared__ float sred[4][80];
    int lane = threadIdx.x & 63, wv = threadIdx.x >> 6;
    #pragma unroll
    for (int t = 0; t < 80; t++){
        float r = acc[t];
        r += __shfl_down(r, 32); r += __shfl_down(r, 16); r += __shfl_down(r, 8);
        r += __shfl_down(r, 4);  r += __shfl_down(r, 2);  r += __shfl_down(r, 1);
        if (lane == 0) sred[wv][t] = r;
    }
    __syncthreads();
    if (threadIdx.x < 80){
        int t = threadIdx.x;
        atomicAdd(&sums[bh*80 + t], sred[0][t]+sred[1][t]+sred[2][t]+sred[3][t]);
    }
}

// ---------------- softmax + Weff = po ∘ attn (per batch) ----------------
__global__ __launch_bounds__(64) void weff_kernel(const float* __restrict__ sums,
                                                  const float* __restrict__ temp,
                                                  const float* __restrict__ po,
                                                  u16* __restrict__ weff){
    int b = blockIdx.x;
    __shared__ float at[8][8][8];
    int t = threadIdx.x;          // 0..63
    {
        int h = t >> 3, i = t & 7;
        const float* f = sums + (b*8 + h)*80;
        float iq = 1.f / fmaxf(sqrtf(f[64+i]), 1e-12f);
        float tv = temp[h];
        float row[8]; float m = -1e30f;
        #pragma unroll
        for (int j = 0; j < 8; j++){
            float ik = 1.f / fmaxf(sqrtf(f[72+j]), 1e-12f);
            row[j] = f[i*8+j]*iq*ik*tv;
            m = fmaxf(m, row[j]);
        }
        float s = 0.f;
        #pragma unroll
        for (int j = 0; j < 8; j++){ row[j] = expf(row[j]-m); s += row[j]; }
        float rs = 1.f/s;
        #pragma unroll
        for (int j = 0; j < 8; j++) at[h][i][j] = row[j]*rs;
    }
    __syncthreads();
    int o = t;
    for (int g = 0; g < 64; g++){
        int h = g >> 3, j = g & 7;
        float wv = 0.f;
        #pragma unroll
        for (int i = 0; i < 8; i++) wv = fmaf(po[o*64 + h*8 + i], at[h][i][j], wv);
        weff[b*4096 + o*64 + g] = f2b(wv);
    }
}

extern "C" void kernel_launch(void* const* d_in, const int* in_sizes, int n_in,
                              void* d_out, int out_size, void* d_ws, size_t ws_size,
                              hipStream_t stream){
    const float* x    = (const float*)d_in[0];
    const float* y    = (const float*)d_in[1];
    const float* ln_w = (const float*)d_in[2];
    const float* ln_b = (const float*)d_in[3];
    const float* temp = (const float*)d_in[4];
    const float* kv_w[2]   = {(const float*)d_in[5],  (const float*)d_in[10]};
    const float* kvdw_w[2] = {(const float*)d_in[6],  (const float*)d_in[11]};
    const float* q_w[2]    = {(const float*)d_in[7],  (const float*)d_in[12]};
    const float* qdw_w[2]  = {(const float*)d_in[8],  (const float*)d_in[13]};
    const float* po_w[2]   = {(const float*)d_in[9],  (const float*)d_in[14]};
    const float* mm_w[2]   = {(const float*)d_in[15], (const float*)d_in[17]};
    const float* mm_b[2]   = {(const float*)d_in[16], (const float*)d_in[18]};

    const size_t HPE = (size_t)BATCH*64*HW;   // elems per 64-ch plane
    u16* PL = (u16*)d_ws;                     // 7 planes
    u16* x1 = PL;            u16* y1 = PL +   HPE;
    u16* A  = PL + 2*HPE;    u16* Bp = PL + 3*HPE;
    u16* C  = PL + 4*HPE;    u16* D  = PL + 5*HPE;
    u16* G  = PL + 6*HPE;
    float* sums = (float*)(PL + 7*HPE);       // 2 * 2560 f32
    u16* warena = (u16*)(sums + 5120);
    // arena offsets (u16): kv0 0, kv1 8192, q0 16384, q1 20480,
    //                      ma0 24576, mb0 32768, ma1 40960, mb1 49152, weff 57344
    const int WKV[2] = {0, 8192}, WQ[2] = {16384, 20480};
    const int WMA[2] = {24576, 40960}, WMB[2] = {32768, 49152};
    const int WEFF = 57344;

    size_t need = 7*HPE*2 + 5120*4 + 73728*2;
    if (ws_size < need) return;

    CvtJobs jobs{}; int nj = 0;
    auto add = [&](const float* s, u16* d, int n){ jobs.j[nj] = {s, d, n}; nj++; };
    for (int br = 0; br < 2; br++){
        add(kv_w[br],        warena + WKV[br],        8192);
        add(q_w[br],         warena + WQ[br],         4096);
        add(mm_w[br],        warena + WMA[br],        4096);  // W0 -> rows 0-63
        add(mm_w[br]+8192,   warena + WMA[br] + 4096, 4096);  // W2 -> rows 64-127
        add(mm_w[br]+4096,   warena + WMB[br],        4096);  // W1 -> rows 0-63
        add(mm_w[br]+12288,  warena + WMB[br] + 4096, 4096);  // W3 -> rows 64-127
    }
    cvt_kernel<<<nj, 256, 0, stream>>>(jobs);
    zero_kernel<<<20, 256, 0, stream>>>(sums, 5120);

    ln2_kernel<<<NPIX/512, 256, 0, stream>>>(x, ln_w, ln_b, x1);
    ln2_kernel<<<NPIX/512, 256, 0, stream>>>(y, ln_w, ln_b, y1);

    float* outp = (float*)d_out;
    const int GT = NPIX/128;     // 2048 gemm tiles
    const int GD = BATCH*64*HW/2048;  // 8192 dw blocks per 64-ch plane
    for (int br = 0; br < 2; br++){
        const u16*   in_kv  = br==0 ? x1 : y1;
        const u16*   in_q   = br==0 ? y1 : x1;
        const float* mod_in = br==0 ? x  : y;
        const float* resid  = br==0 ? y  : x;
        float* sb = sums + br*2560;

        // kv conv (M=128) -> A(k-pre), B(v-pre)
        gemm_kernel<8,2,false,0,u16><<<GT, 256, 0, stream>>>(
            in_kv, in_kv, warena + WKV[br], nullptr, nullptr, A, Bp, nullptr, nullptr, nullptr);
        // depthwise on both halves: A->C (k), B->D (v)
        dw8_kernel<<<GD, 256, 0, stream>>>(A,  kvdw_w[br], 0,  C);
        dw8_kernel<<<GD, 256, 0, stream>>>(Bp, kvdw_w[br], 64, D);
        // q conv (M=64) -> A, then depthwise A->B
        gemm_kernel<4,2,false,0,u16><<<GT, 256, 0, stream>>>(
            in_q, in_q, warena + WQ[br], nullptr, nullptr, A, nullptr, nullptr, nullptr, nullptr);
        dw8_kernel<<<GD, 256, 0, stream>>>(A, qdw_w[br], 0, Bp);
        // modulation conv-a (stacked M=128, f32 input) -> A (m1), G (m2), bias+lrelu
        gemm_kernel<8,2,false,1,float><<<GT, 256, 0, stream>>>(
            mod_in, mod_in, warena + WMA[br], mm_b[br], mm_b[br]+128, A, G, nullptr, nullptr, nullptr);
        // modulation conv-b (block-diag M=128,K=128) + fused vmod on D
        gemm_kernel<8,4,true,2,u16><<<GT, 256, 0, stream>>>(
            A, G, warena + WMB[br], mm_b[br]+64, mm_b[br]+192, nullptr, nullptr, D, nullptr, nullptr);
        // attention stats (q = B, k = C) -> sums, then softmax + Weff
        attn_part_kernel<<<BATCH*8*NSL, 256, 0, stream>>>(Bp, C, sb);
        weff_kernel<<<BATCH, 64, 0, stream>>>(sb, temp, po_w[br], warena + WEFF);
        // final: Weff x V + resid -> f32 out
        gemm_kernel<4,2,false,3,u16><<<GT, 256, 0, stream>>>(
            D, D, warena + WEFF, nullptr, nullptr, nullptr, nullptr, nullptr,
            resid, outp + (size_t)br*HPE);
    }
}

// Round 2
// 760.287 us; speedup vs baseline: 1.1636x; 1.0787x over previous
//
#include <hip/hip_runtime.h>
#include <hip/hip_bf16.h>

#define HW 65536
#define BATCH 4
#define NPIX (BATCH*HW)   // 262144 pixels

typedef unsigned short u16;
typedef unsigned int   u32;
typedef __attribute__((ext_vector_type(8))) short bh8;   // 8 bf16 (A/B frag, 4 VGPRs)
typedef __attribute__((ext_vector_type(4))) float f4;    // 4 f32 (C/D frag)

__device__ __forceinline__ float b2f(u16 u){
    u32 i = ((u32)u) << 16; float f; __builtin_memcpy(&f, &i, 4); return f;
}
__device__ __forceinline__ u16 f2b(float f){
    __hip_bfloat16 h = __float2bfloat16(f); u16 u; __builtin_memcpy(&u, &h, 2); return u;
}

__device__ __forceinline__ f4 mfma16(bh8 a, bh8 b, f4 c){
    return __builtin_amdgcn_mfma_f32_16x16x32_bf16(a, b, c, 0, 0, 0);
}

// ---------------- weight conversion (f32 -> bf16 arena, optional col scale) ----------------
struct CvtJob { const float* src; u16* dst; int n; const float* cs; };
struct CvtJobs { CvtJob j[12]; };
__global__ void cvt_kernel(CvtJobs jobs){
    const CvtJob J = jobs.j[blockIdx.x];
    if (J.cs){
        for (int i = threadIdx.x; i < J.n; i += 256) J.dst[i] = f2b(J.src[i] * J.cs[i & 63]);
    } else {
        for (int i = threadIdx.x; i < J.n; i += 256) J.dst[i] = f2b(J.src[i]);
    }
}

// ---------------- prep: zero sums + LN rowsum constants ----------------
// lnc layout (f32): kv0 rs[128] rb[128] | kv1 rs rb | q0 rs[64] rb[64] | q1 rs rb  (768 total)
__global__ __launch_bounds__(256) void prep_kernel(const float* __restrict__ kv0w,
                                                   const float* __restrict__ kv1w,
                                                   const float* __restrict__ q0w,
                                                   const float* __restrict__ q1w,
                                                   const float* __restrict__ lnw,
                                                   const float* __restrict__ lnb,
                                                   float* __restrict__ sums,
                                                   float* __restrict__ lnc){
    int blk = blockIdx.x;
    if (blk == 0){
        for (int i = threadIdx.x; i < 5120; i += 256) sums[i] = 0.f;
    } else if (blk <= 2){
        const float* W = (blk == 1) ? kv0w : kv1w;
        float* rs = lnc + (blk-1)*256;
        int o = threadIdx.x;
        if (o < 128){
            float a = 0.f, bb = 0.f;
            for (int c = 0; c < 64; c++){
                float wv = W[o*64 + c];
                a = fmaf(wv, lnw[c], a); bb = fmaf(wv, lnb[c], bb);
            }
            rs[o] = a; rs[128 + o] = bb;
        }
    } else {
        const float* W = (blk == 3) ? q0w : q1w;
        float* rs = lnc + 512 + (blk-3)*128;
        int o = threadIdx.x;
        if (o < 64){
            float a = 0.f, bb = 0.f;
            for (int c = 0; c < 64; c++){
                float wv = W[o*64 + c];
                a = fmaf(wv, lnw[c], a); bb = fmaf(wv, lnb[c], bb);
            }
            rs[o] = a; rs[64 + o] = bb;
        }
    }
}

// ---------------- MFMA GEMM over pixels ----------------
// M = MT*16 out-channels, K = KT*32 in-channels. Input planes are [B][64][HW].
// Lane owns adjacent pixel pair {pbase, pbase+1} (frag0 = even, frag1 = odd).
// LNF: input is RAW f32; LN is folded: out = inv*(Wl·x - mu*rs[o]) + rb[o]
//      (weights pre-scaled by ln_w in cvt; rs/rb from prep_kernel).
// EPI: 0 = store bf16 planes (split at ch 64), 3 = +f32 resid, f32 store,
//      per-batch Weff A-matrix.
template<int MT, int KT, int EPI, typename TB, bool LNF>
__global__ __launch_bounds__(256) void gemm_kernel(
        const TB* __restrict__ inLo, const TB* __restrict__ inHi,
        const u16* __restrict__ WA,
        const float* __restrict__ rs, const float* __restrict__ rb,
        u16* __restrict__ outLo, u16* __restrict__ outHi,
        const float* __restrict__ resid, float* __restrict__ outF){
    constexpr int KD = KT*32;
    int tile = blockIdx.x;                          // NPIX/128 tiles
    int w = threadIdx.x >> 6, lane = threadIdx.x & 63;
    int quad = lane >> 4, l16 = lane & 15;
    int b = tile >> 9;                              // 512 tiles per batch
    int pbase = ((tile & 511) << 7) + (w << 5) + (l16 << 1);  // even pixel

    bh8 a[MT][KT];
    const u16* wbase = (EPI == 3) ? (WA + b*4096) : WA;
    #pragma unroll
    for (int mi = 0; mi < MT; mi++){
        int row = mi*16 + l16;
        #pragma unroll
        for (int ks = 0; ks < KT; ks++)
            __builtin_memcpy(&a[mi][ks], wbase + row*KD + ks*32 + quad*8, 16);
    }
    f4 acc[MT][2];
    #pragma unroll
    for (int mi = 0; mi < MT; mi++){ acc[mi][0] = (f4){0.f,0.f,0.f,0.f}; acc[mi][1] = (f4){0.f,0.f,0.f,0.f}; }

    float s1a = 0.f, s2a = 0.f, s1b = 0.f, s2b = 0.f;   // LN stats (LNF)
    #pragma unroll
    for (int ks = 0; ks < KT; ks++){
        int kblk = ks*32 + quad*8;
        const TB* base = (kblk < 64) ? inLo : inHi;
        const TB* pp = base + ((size_t)b*64 + (kblk & 63))*HW + pbase;
        bh8 b0, b1;
        #pragma unroll
        for (int j = 0; j < 8; j++){
            if constexpr (sizeof(TB) == 2){
                u32 m = *(const u32*)(pp + (size_t)j*HW);
                b0[j] = (short)(m & 0xffffu);
                b1[j] = (short)(m >> 16);
            } else {
                float2 f = *(const float2*)(pp + (size_t)j*HW);
                if constexpr (LNF){
                    s1a += f.x; s2a = fmaf(f.x, f.x, s2a);
                    s1b += f.y; s2b = fmaf(f.y, f.y, s2b);
                }
                b0[j] = (short)f2b(f.x);
                b1[j] = (short)f2b(f.y);
            }
        }
        #pragma unroll
        for (int mi = 0; mi < MT; mi++){
            acc[mi][0] = mfma16(a[mi][ks], b0, acc[mi][0]);
            acc[mi][1] = mfma16(a[mi][ks], b1, acc[mi][1]);
        }
    }

    float mu0 = 0.f, iv0 = 1.f, mu1 = 0.f, iv1 = 1.f;
    if constexpr (LNF){
        s1a += __shfl_xor(s1a, 16); s1a += __shfl_xor(s1a, 32);
        s2a += __shfl_xor(s2a, 16); s2a += __shfl_xor(s2a, 32);
        s1b += __shfl_xor(s1b, 16); s1b += __shfl_xor(s1b, 32);
        s2b += __shfl_xor(s2b, 16); s2b += __shfl_xor(s2b, 32);
        mu0 = s1a*(1.f/64.f); iv0 = rsqrtf(s2a*(1.f/64.f) - mu0*mu0 + 1e-5f);
        mu1 = s1b*(1.f/64.f); iv1 = rsqrtf(s2b*(1.f/64.f) - mu1*mu1 + 1e-5f);
    }

    #pragma unroll
    for (int mi = 0; mi < MT; mi++)
    #pragma unroll
    for (int r = 0; r < 4; r++){
        int o = mi*16 + quad*4 + r;
        size_t pidx = ((size_t)b*64 + (o & 63))*HW + pbase;
        float va0 = acc[mi][0][r];
        float va1 = acc[mi][1][r];
        if constexpr (EPI == 3){
            float2 rr = *(const float2*)(resid + pidx);
            float2 st; st.x = va0 + rr.x; st.y = va1 + rr.y;
            *(float2*)(outF + pidx) = st;
        } else {
            if constexpr (LNF){
                float rsv = rs[o], rbv = rb[o];
                va0 = iv0*(va0 - mu0*rsv) + rbv;
                va1 = iv1*(va1 - mu1*rsv) + rbv;
            }
            u16* dst = (o < 64) ? outLo : outHi;
            *(u32*)(dst + pidx) = (u32)f2b(va0) | ((u32)f2b(va1) << 16);
        }
    }
}

// ---------------- fused modulation: s,t = MLPs of raw in; v' = v*(s+1)+t ----------------
// Stage1: M=128,K=64 on raw f32 input (+bias, lrelu) -> LDS (bf16 pairs).
// Stage2: M=128 block-diag K=128 from LDS -> vmod epilogue on vP.
// LDS: [128 ch][65 u32] rows; pixel-pair swizzle ((ch>>2)&3)*4 => 2-way banks both sides.
__global__ __launch_bounds__(256) void modfused_kernel(
        const float* __restrict__ in,
        const u16* __restrict__ WA, const u16* __restrict__ WB,
        const float* __restrict__ b0v, const float* __restrict__ b2v,
        const float* __restrict__ b1v, const float* __restrict__ b3v,
        u16* __restrict__ vP){
    __shared__ u32 lds[128*65];
    int tile = blockIdx.x;
    int w = threadIdx.x >> 6, lane = threadIdx.x & 63;
    int quad = lane >> 4, l16 = lane & 15;
    int b = tile >> 9;
    int pbase = ((tile & 511) << 7) + (w << 5) + (l16 << 1);
    int pxp = (w << 4) + l16;     // pixel-pair index within tile (0..63)

    // ---- stage 1 ----
    bh8 a1[8][2];
    #pragma unroll
    for (int mi = 0; mi < 8; mi++)
        #pragma unroll
        for (int ks = 0; ks < 2; ks++)
            __builtin_memcpy(&a1[mi][ks], WA + (mi*16+l16)*64 + ks*32 + quad*8, 16);
    f4 acc[8][2];
    #pragma unroll
    for (int mi = 0; mi < 8; mi++){ acc[mi][0] = (f4){0.f,0.f,0.f,0.f}; acc[mi][1] = (f4){0.f,0.f,0.f,0.f}; }
    #pragma unroll
    for (int ks = 0; ks < 2; ks++){
        const float* pp = in + ((size_t)b*64 + ks*32 + quad*8)*HW + pbase;
        bh8 f0, f1;
        #pragma unroll
        for (int j = 0; j < 8; j++){
            float2 f = *(const float2*)(pp + (size_t)j*HW);
            f0[j] = (short)f2b(f.x);
            f1[j] = (short)f2b(f.y);
        }
        #pragma unroll
        for (int mi = 0; mi < 8; mi++){
            acc[mi][0] = mfma16(a1[mi][ks], f0, acc[mi][0]);
            acc[mi][1] = mfma16(a1[mi][ks], f1, acc[mi][1]);
        }
    }
    #pragma unroll
    for (int mi = 0; mi < 8; mi++)
    #pragma unroll
    for (int r = 0; r < 4; r++){
        int o = mi*16 + quad*4 + r;
        float bi = (o < 64) ? b0v[o] : b2v[o-64];
        float v0 = acc[mi][0][r] + bi; v0 = v0 > 0.f ? v0 : 0.1f*v0;
        float v1 = acc[mi][1][r] + bi; v1 = v1 > 0.f ? v1 : 0.1f*v1;
        lds[o*65 + ((pxp + ((o>>2)&3)*4) & 63)] = (u32)f2b(v0) | ((u32)f2b(v1) << 16);
    }
    __syncthreads();

    // ---- stage 2 (block-diag: rows 0-63 x ch 0-63 (m1), rows 64-127 x ch 64-127 (m2)) ----
    bh8 a2[8][2];
    #pragma unroll
    for (int mi = 0; mi < 8; mi++)
        #pragma unroll
        for (int ks = 0; ks < 2; ks++)
            __builtin_memcpy(&a2[mi][ks], WB + (mi*16+l16)*64 + ks*32 + quad*8, 16);
    f4 acc2[8][2];
    #pragma unroll
    for (int mi = 0; mi < 8; mi++){ acc2[mi][0] = (f4){0.f,0.f,0.f,0.f}; acc2[mi][1] = (f4){0.f,0.f,0.f,0.f}; }
    #pragma unroll
    for (int ks = 0; ks < 4; ks++){
        int kb = ks*32 + quad*8;
        bh8 bb0, bb1;
        #pragma unroll
        for (int j = 0; j < 8; j++){
            int ch = kb + j;
            u32 m = lds[ch*65 + ((pxp + ((ch>>2)&3)*4) & 63)];
            bb0[j] = (short)(m & 0xffffu);
            bb1[j] = (short)(m >> 16);
        }
        #pragma unroll
        for (int mi = 0; mi < 8; mi++){
            if (mi < 4 ? (ks < 2) : (ks >= 2)){
                int ksl = (mi >= 4) ? ks - 2 : ks;
                acc2[mi][0] = mfma16(a2[mi][ksl], bb0, acc2[mi][0]);
                acc2[mi][1] = mfma16(a2[mi][ksl], bb1, acc2[mi][1]);
            }
        }
    }
    // ---- vmod epilogue ----
    #pragma unroll
    for (int mi = 0; mi < 4; mi++)
    #pragma unroll
    for (int r = 0; r < 4; r++){
        int o = mi*16 + quad*4 + r;
        size_t pidx = ((size_t)b*64 + o)*HW + pbase;
        float s0 = acc2[mi][0][r] + b1v[o];
        float s1 = acc2[mi][1][r] + b1v[o];
        float t0 = acc2[mi+4][0][r] + b3v[o];
        float t1 = acc2[mi+4][1][r] + b3v[o];
        u32 vv = *(u32*)(vP + pidx);
        float v0 = b2f((u16)(vv & 0xffffu)), v1 = b2f((u16)(vv >> 16));
        *(u32*)(vP + pidx) = (u32)f2b(v0*(s0+1.f)+t0)
                           | ((u32)f2b(v1*(s1+1.f)+t1) << 16);
    }
}

// ---------------- depthwise 3x3, 3 planes in one dispatch, 8 px/thread ----------------
struct DwArgs { const u16* in0; const u16* in1; const u16* in2;
                u16* out0; u16* out1; u16* out2;
                const float* w0; const float* w1; const float* w2;
                int c0, c1, c2; };
__global__ __launch_bounds__(256) void dw3_kernel(DwArgs A){
    int seg = blockIdx.x >> 13;                  // 8192 blocks per plane
    int lid = ((blockIdx.x & 8191) << 8) + threadIdx.x;
    const u16* inp = seg == 0 ? A.in0 : seg == 1 ? A.in1 : A.in2;
    u16* outp      = seg == 0 ? A.out0 : seg == 1 ? A.out1 : A.out2;
    const float* wd = seg == 0 ? A.w0 : seg == 1 ? A.w1 : A.w2;
    int choff      = seg == 0 ? A.c0 : seg == 1 ? A.c1 : A.c2;
    int bc = lid >> 13;
    int n8 = lid & 8191;
    int h = n8 >> 5, c8 = (n8 & 31) << 3;
    const float* wc = wd + ((size_t)((bc & 63) + choff))*9;
    const u16* p = inp + (size_t)bc*HW;
    float row[3][10];
    #pragma unroll
    for (int r = 0; r < 3; r++){
        int hh = h - 1 + r;
        bool ok = (unsigned)hh < 256u;
        const u16* pr = p + hh*256 + c8;
        if (ok){
            uint4 m = *(const uint4*)pr;          // 8 bf16
            row[r][1] = b2f((u16)m.x); row[r][2] = b2f((u16)(m.x>>16));
            row[r][3] = b2f((u16)m.y); row[r][4] = b2f((u16)(m.y>>16));
            row[r][5] = b2f((u16)m.z); row[r][6] = b2f((u16)(m.z>>16));
            row[r][7] = b2f((u16)m.w); row[r][8] = b2f((u16)(m.w>>16));
            row[r][0] = (c8 > 0)   ? b2f(pr[-1]) : 0.f;
            row[r][9] = (c8 < 248) ? b2f(pr[8])  : 0.f;
        } else {
            #pragma unroll
            for (int j = 0; j < 10; j++) row[r][j] = 0.f;
        }
    }
    float o[8];
    #pragma unroll
    for (int i = 0; i < 8; i++){
        float a = 0.f;
        #pragma unroll
        for (int r = 0; r < 3; r++){
            a = fmaf(wc[r*3+0], row[r][i],   a);
            a = fmaf(wc[r*3+1], row[r][i+1], a);
            a = fmaf(wc[r*3+2], row[r][i+2], a);
        }
        o[i] = a;
    }
    uint4 st;
    st.x = (u32)f2b(o[0]) | ((u32)f2b(o[1])<<16);
    st.y = (u32)f2b(o[2]) | ((u32)f2b(o[3])<<16);
    st.z = (u32)f2b(o[4]) | ((u32)f2b(o[5])<<16);
    st.w = (u32)f2b(o[6]) | ((u32)f2b(o[7])<<16);
    *(uint4*)(outp + (size_t)bc*HW + h*256 + c8) = st;
}

// ---------------- attention partial sums (Gram + norms), atomic ----------------
#define NSL 64
__global__ __launch_bounds__(256) void attn_part_kernel(const u16* __restrict__ q,
                                                        const u16* __restrict__ k,
                                                        float* __restrict__ sums){
    int blk = blockIdx.x;            // B*8*NSL
    int sl = blk & (NSL-1);
    int bh = blk >> 6;               // b*8+h
    int b = bh >> 3, h = bh & 7;
    const u16* qp = q + ((size_t)b*64 + h*8)*HW + sl*(HW/NSL);
    const u16* kp = k + ((size_t)b*64 + h*8)*HW + sl*(HW/NSL);
    float acc[80];
    #pragma unroll
    for (int i = 0; i < 80; i++) acc[i] = 0.f;
    int n0 = threadIdx.x << 2;       // 256 threads * 4 px = 1024 = HW/NSL
    float qv[8][4], kw[8][4];
    #pragma unroll
    for (int i = 0; i < 8; i++){
        uint2 mq = *(const uint2*)(qp + (size_t)i*HW + n0);
        uint2 mk = *(const uint2*)(kp + (size_t)i*HW + n0);
        qv[i][0] = b2f((u16)(mq.x & 0xffffu)); qv[i][1] = b2f((u16)(mq.x >> 16));
        qv[i][2] = b2f((u16)(mq.y & 0xffffu)); qv[i][3] = b2f((u16)(mq.y >> 16));
        kw[i][0] = b2f((u16)(mk.x & 0xffffu)); kw[i][1] = b2f((u16)(mk.x >> 16));
        kw[i][2] = b2f((u16)(mk.y & 0xffffu)); kw[i][3] = b2f((u16)(mk.y >> 16));
    }
    #pragma unroll
    for (int i = 0; i < 8; i++){
        #pragma unroll
        for (int u = 0; u < 4; u++){
            acc[64+i] = fmaf(qv[i][u], qv[i][u], acc[64+i]);
            acc[72+i] = fmaf(kw[i][u], kw[i][u], acc[72+i]);
        }
        #pragma unroll
        for (int j = 0; j < 8; j++)
            #pragma unroll
            for (int u = 0; u < 4; u++)
                acc[i*8+j] = fmaf(qv[i][u], kw[j][u], acc[i*8+j]);
    }
    __shared__ float sred[4][80];
    int lane = threadIdx.x & 63, wv = threadIdx.x >> 6;
    #pragma unroll
    for (int t = 0; t < 80; t++){
        float r = acc[t];
        r += __shfl_down(r, 32); r += __shfl_down(r, 16); r += __shfl_down(r, 8);
        r += __shfl_down(r, 4);  r += __shfl_down(r, 2);  r += __shfl_down(r, 1);
        if (lane == 0) sred[wv][t] = r;
    }
    __syncthreads();
    if (threadIdx.x < 80){
        int t = threadIdx.x;
        atomicAdd(&sums[bh*80 + t], sred[0][t]+sred[1][t]+sred[2][t]+sred[3][t]);
    }
}

// ---------------- softmax + Weff = po ∘ attn (per batch) ----------------
__global__ __launch_bounds__(64) void weff_kernel(const float* __restrict__ sums,
                                                  const float* __restrict__ temp,
                                                  const float* __restrict__ po,
                                                  u16* __restrict__ weff){
    int b = blockIdx.x;
    __shared__ float at[8][8][8];
    int t = threadIdx.x;          // 0..63
    {
        int h = t >> 3, i = t & 7;
        const float* f = sums + (b*8 + h)*80;
        float iq = 1.f / fmaxf(sqrtf(f[64+i]), 1e-12f);
        float tv = temp[h];
        float row[8]; float m = -1e30f;
        #pragma unroll
        for (int j = 0; j < 8; j++){
            float ik = 1.f / fmaxf(sqrtf(f[72+j]), 1e-12f);
            row[j] = f[i*8+j]*iq*ik*tv;
            m = fmaxf(m, row[j]);
        }
        float s = 0.f;
        #pragma unroll
        for (int j = 0; j < 8; j++){ row[j] = expf(row[j]-m); s += row[j]; }
        float rs = 1.f/s;
        #pragma unroll
        for (int j = 0; j < 8; j++) at[h][i][j] = row[j]*rs;
    }
    __syncthreads();
    int o = t;
    for (int g = 0; g < 64; g++){
        int h = g >> 3, j = g & 7;
        float wv = 0.f;
        #pragma unroll
        for (int i = 0; i < 8; i++) wv = fmaf(po[o*64 + h*8 + i], at[h][i][j], wv);
        weff[b*4096 + o*64 + g] = f2b(wv);
    }
}

extern "C" void kernel_launch(void* const* d_in, const int* in_sizes, int n_in,
                              void* d_out, int out_size, void* d_ws, size_t ws_size,
                              hipStream_t stream){
    const float* x    = (const float*)d_in[0];
    const float* y    = (const float*)d_in[1];
    const float* ln_w = (const float*)d_in[2];
    const float* ln_b = (const float*)d_in[3];
    const float* temp = (const float*)d_in[4];
    const float* kv_w[2]   = {(const float*)d_in[5],  (const float*)d_in[10]};
    const float* kvdw_w[2] = {(const float*)d_in[6],  (const float*)d_in[11]};
    const float* q_w[2]    = {(const float*)d_in[7],  (const float*)d_in[12]};
    const float* qdw_w[2]  = {(const float*)d_in[8],  (const float*)d_in[13]};
    const float* po_w[2]   = {(const float*)d_in[9],  (const float*)d_in[14]};
    const float* mm_w[2]   = {(const float*)d_in[15], (const float*)d_in[17]};
    const float* mm_b[2]   = {(const float*)d_in[16], (const float*)d_in[18]};

    const size_t HPE = (size_t)BATCH*64*HW;   // elems per 64-ch plane
    u16* PL = (u16*)d_ws;                     // 6 planes
    u16* P0 = PL;            u16* P1 = PL +   HPE;
    u16* P2 = PL + 2*HPE;    u16* P3 = PL + 3*HPE;
    u16* P4 = PL + 4*HPE;    u16* P5 = PL + 5*HPE;
    float* sums = (float*)(PL + 6*HPE);       // 2 * 2560 f32
    float* lnc  = sums + 5120;                // 768 f32 LN rowsum constants
    u16* warena = (u16*)(lnc + 768);
    // arena offsets (u16): kv0 0, kv1 8192, q0 16384, q1 20480,
    //                      ma0 24576, mb0 32768, ma1 40960, mb1 49152, weff 57344
    const int WKV[2] = {0, 8192}, WQ[2] = {16384, 20480};
    const int WMA[2] = {24576, 40960}, WMB[2] = {32768, 49152};
    const int WEFF = 57344;

    size_t need = 6*HPE*2 + (5120+768)*4 + 73728*2;
    if (ws_size < need) return;

    CvtJobs jobs{}; int nj = 0;
    auto add = [&](const float* s, u16* d, int n, const float* cs){ jobs.j[nj] = {s, d, n, cs}; nj++; };
    for (int br = 0; br < 2; br++){
        add(kv_w[br],        warena + WKV[br],        8192, ln_w);  // Wl = W * ln_w[col]
        add(q_w[br],         warena + WQ[br],         4096, ln_w);
        add(mm_w[br],        warena + WMA[br],        4096, nullptr);  // W0 -> rows 0-63
        add(mm_w[br]+8192,   warena + WMA[br] + 4096, 4096, nullptr);  // W2 -> rows 64-127
        add(mm_w[br]+4096,   warena + WMB[br],        4096, nullptr);  // W1 -> rows 0-63
        add(mm_w[br]+12288,  warena + WMB[br] + 4096, 4096, nullptr);  // W3 -> rows 64-127
    }
    cvt_kernel<<<nj, 256, 0, stream>>>(jobs);
    prep_kernel<<<5, 256, 0, stream>>>(kv_w[0], kv_w[1], q_w[0], q_w[1],
                                       ln_w, ln_b, sums, lnc);

    float* outp = (float*)d_out;
    const int GT = NPIX/128;     // 2048 gemm tiles
    for (int br = 0; br < 2; br++){
        const float* in_kv  = br==0 ? x  : y;   // raw f32 (LN folded into gemm)
        const float* in_q   = br==0 ? y  : x;
        const float* mod_in = br==0 ? x  : y;
        const float* resid  = br==0 ? y  : x;
        float* sb = sums + br*2560;
        const float* rs_kv = lnc + br*256;          // rs[128], rb at +128
        const float* rs_q  = lnc + 512 + br*128;    // rs[64], rb at +64

        // kv conv (M=128, LN-folded) -> P0(k-pre), P1(v-pre)
        gemm_kernel<8,2,0,float,true><<<GT, 256, 0, stream>>>(
            in_kv, in_kv, warena + WKV[br], rs_kv, rs_kv+128, P0, P1, nullptr, nullptr);
        // q conv (M=64, LN-folded) -> P2
        gemm_kernel<4,2,0,float,true><<<GT, 256, 0, stream>>>(
            in_q, in_q, warena + WQ[br], rs_q, rs_q+64, P2, P2, nullptr, nullptr);
        // depthwise all 3 planes: P0->P3 (k), P1->P4 (v), P2->P5 (q)
        DwArgs da{P0, P1, P2, P3, P4, P5,
                  kvdw_w[br], kvdw_w[br], qdw_w[br], 0, 64, 0};
        dw3_kernel<<<3*8192, 256, 0, stream>>>(da);
        // fused modulation (two 1x1 MLP stages via LDS) + vmod on P4
        modfused_kernel<<<GT, 256, 0, stream>>>(
            mod_in, warena + WMA[br], warena + WMB[br],
            mm_b[br], mm_b[br]+128, mm_b[br]+64, mm_b[br]+192, P4);
        // attention stats (q = P5, k = P3) -> sums, then softmax + Weff
        attn_part_kernel<<<BATCH*8*NSL, 256, 0, stream>>>(P5, P3, sb);
        weff_kernel<<<BATCH, 64, 0, stream>>>(sb, temp, po_w[br], warena + WEFF);
        // final: Weff x V + resid -> f32 out
        gemm_kernel<4,2,3,u16,false><<<GT, 256, 0, stream>>>(
            P4, P4, warena + WEFF, nullptr, nullptr, nullptr, nullptr,
            resid, outp + (size_t)br*HPE);
    }
}

// Round 3
// 741.519 us; speedup vs baseline: 1.1931x; 1.0253x over previous
//
#include <hip/hip_runtime.h>
#include <hip/hip_bf16.h>

#define HW 65536
#define BATCH 4
#define NPIX (BATCH*HW)   // 262144 pixels

typedef unsigned short u16;
typedef unsigned int   u32;
typedef __attribute__((ext_vector_type(8))) short bh8;   // 8 bf16 (A/B frag, 4 VGPRs)
typedef __attribute__((ext_vector_type(4))) float f4;    // 4 f32 (C/D frag)

__device__ __forceinline__ float b2f(u16 u){
    u32 i = ((u32)u) << 16; float f; __builtin_memcpy(&f, &i, 4); return f;
}
__device__ __forceinline__ u16 f2b(float f){
    __hip_bfloat16 h = __float2bfloat16(f); u16 u; __builtin_memcpy(&u, &h, 2); return u;
}

__device__ __forceinline__ f4 mfma16(bh8 a, bh8 b, f4 c){
    return __builtin_amdgcn_mfma_f32_16x16x32_bf16(a, b, c, 0, 0, 0);
}

// ---------------- setup: weight cvt + LN rowsums + zero sums, one dispatch ----------------
struct CvtJob { const float* src; u16* dst; int n; const float* cs; };
struct SetupArgs {
    CvtJob j[12];
    const float* kvw[2]; const float* qw[2];
    const float* lnw; const float* lnb;
    float* sums; float* lnc;
};
__global__ __launch_bounds__(256) void setup_kernel(SetupArgs S){
    int blk = blockIdx.x;
    if (blk < 12){
        const CvtJob J = S.j[blk];
        if (J.cs){
            for (int i = threadIdx.x; i < J.n; i += 256) J.dst[i] = f2b(J.src[i] * J.cs[i & 63]);
        } else {
            for (int i = threadIdx.x; i < J.n; i += 256) J.dst[i] = f2b(J.src[i]);
        }
        return;
    }
    int pb = blk - 12;
    if (pb == 0){
        for (int i = threadIdx.x; i < 5120; i += 256) S.sums[i] = 0.f;
    } else if (pb <= 2){
        const float* W = S.kvw[pb-1];
        float* rs = S.lnc + (pb-1)*256;
        int o = threadIdx.x;
        if (o < 128){
            float a = 0.f, bb = 0.f;
            for (int c = 0; c < 64; c++){
                float wv = W[o*64 + c];
                a = fmaf(wv, S.lnw[c], a); bb = fmaf(wv, S.lnb[c], bb);
            }
            rs[o] = a; rs[128 + o] = bb;
        }
    } else {
        const float* W = S.qw[pb-3];
        float* rs = S.lnc + 512 + (pb-3)*128;
        int o = threadIdx.x;
        if (o < 64){
            float a = 0.f, bb = 0.f;
            for (int c = 0; c < 64; c++){
                float wv = W[o*64 + c];
                a = fmaf(wv, S.lnw[c], a); bb = fmaf(wv, S.lnb[c], bb);
            }
            rs[o] = a; rs[64 + o] = bb;
        }
    }
}

// ---------------- LN-folded 1x1 conv GEMM, dual-branch, LDS-staged weights ----------------
// out = inv*(Wl.x - mu*rs[o]) + rb[o]; weights pre-scaled by ln_w.
// Weight LDS chunk-swizzle: chunk ^= (row&7) -> a-frag ds_read is 2-way banked (free).
struct GemmDual {
    const float* in[2];
    const u16* wa[2];
    const float* rs[2]; const float* rb[2];
    u16* outLo[2]; u16* outHi[2];
};
template<int MT>
__global__ __launch_bounds__(256,4) void gemmln_kernel(GemmDual G){
    constexpr int KD = 64;
    constexpr int NW = MT*16*KD;
    __shared__ u16 wl[NW];
    int seg = blockIdx.x >> 11, tile = blockIdx.x & 2047;
    {
        const u16* W = G.wa[seg];
        for (int i = threadIdx.x; i < NW/8; i += 256){
            int row = i >> 3, ch = i & 7;
            uint4 v = *(const uint4*)(W + row*KD + ch*8);
            *(uint4*)(wl + row*KD + ((ch ^ (row & 7)) << 3)) = v;
        }
    }
    __syncthreads();

    int w = threadIdx.x >> 6, lane = threadIdx.x & 63;
    int quad = lane >> 4, l16 = lane & 15;
    int b = tile >> 9;
    int pbase = ((tile & 511) << 7) + (w << 5) + (l16 << 1);

    f4 acc[MT][2];
    #pragma unroll
    for (int mi = 0; mi < MT; mi++){ acc[mi][0] = (f4){0.f,0.f,0.f,0.f}; acc[mi][1] = (f4){0.f,0.f,0.f,0.f}; }

    float s1a = 0.f, s2a = 0.f, s1b = 0.f, s2b = 0.f;
    #pragma unroll
    for (int ks = 0; ks < 2; ks++){
        const float* pp = G.in[seg] + ((size_t)b*64 + ks*32 + quad*8)*HW + pbase;
        bh8 b0, b1;
        #pragma unroll
        for (int j = 0; j < 8; j++){
            float2 f = *(const float2*)(pp + (size_t)j*HW);
            s1a += f.x; s2a = fmaf(f.x, f.x, s2a);
            s1b += f.y; s2b = fmaf(f.y, f.y, s2b);
            b0[j] = (short)f2b(f.x);
            b1[j] = (short)f2b(f.y);
        }
        #pragma unroll
        for (int mi = 0; mi < MT; mi++){
            bh8 a;
            __builtin_memcpy(&a, wl + (mi*16 + l16)*KD + ((((ks<<2)+quad) ^ (l16 & 7)) << 3), 16);
            acc[mi][0] = mfma16(a, b0, acc[mi][0]);
            acc[mi][1] = mfma16(a, b1, acc[mi][1]);
        }
    }

    s1a += __shfl_xor(s1a, 16); s1a += __shfl_xor(s1a, 32);
    s2a += __shfl_xor(s2a, 16); s2a += __shfl_xor(s2a, 32);
    s1b += __shfl_xor(s1b, 16); s1b += __shfl_xor(s1b, 32);
    s2b += __shfl_xor(s2b, 16); s2b += __shfl_xor(s2b, 32);
    float mu0 = s1a*(1.f/64.f), iv0 = rsqrtf(s2a*(1.f/64.f) - mu0*mu0 + 1e-5f);
    float mu1 = s1b*(1.f/64.f), iv1 = rsqrtf(s2b*(1.f/64.f) - mu1*mu1 + 1e-5f);

    const float* rs = G.rs[seg]; const float* rb = G.rb[seg];
    u16* oLo = G.outLo[seg]; u16* oHi = G.outHi[seg];
    #pragma unroll
    for (int mi = 0; mi < MT; mi++)
    #pragma unroll
    for (int r = 0; r < 4; r++){
        int o = mi*16 + quad*4 + r;
        size_t pidx = ((size_t)b*64 + (o & 63))*HW + pbase;
        float rsv = rs[o], rbv = rb[o];
        float va0 = iv0*(acc[mi][0][r] - mu0*rsv) + rbv;
        float va1 = iv1*(acc[mi][1][r] - mu1*rsv) + rbv;
        u16* dst = (o < 64) ? oLo : oHi;
        *(u32*)(dst + pidx) = (u32)f2b(va0) | ((u32)f2b(va1) << 16);
    }
}

// ---------------- depthwise 3x3, 3 planes per dispatch, 8 px/thread ----------------
struct DwArgs { const u16* in0; const u16* in1; const u16* in2;
                u16* out0; u16* out1; u16* out2;
                const float* w0; const float* w1; const float* w2;
                int c0, c1, c2; };
__global__ __launch_bounds__(256) void dw3_kernel(DwArgs A){
    int seg = blockIdx.x >> 13;
    int lid = ((blockIdx.x & 8191) << 8) + threadIdx.x;
    const u16* inp = seg == 0 ? A.in0 : seg == 1 ? A.in1 : A.in2;
    u16* outp      = seg == 0 ? A.out0 : seg == 1 ? A.out1 : A.out2;
    const float* wd = seg == 0 ? A.w0 : seg == 1 ? A.w1 : A.w2;
    int choff      = seg == 0 ? A.c0 : seg == 1 ? A.c1 : A.c2;
    int bc = lid >> 13;
    int n8 = lid & 8191;
    int h = n8 >> 5, c8 = (n8 & 31) << 3;
    const float* wc = wd + ((size_t)((bc & 63) + choff))*9;
    const u16* p = inp + (size_t)bc*HW;
    float row[3][10];
    #pragma unroll
    for (int r = 0; r < 3; r++){
        int hh = h - 1 + r;
        bool ok = (unsigned)hh < 256u;
        const u16* pr = p + hh*256 + c8;
        if (ok){
            uint4 m = *(const uint4*)pr;
            row[r][1] = b2f((u16)m.x); row[r][2] = b2f((u16)(m.x>>16));
            row[r][3] = b2f((u16)m.y); row[r][4] = b2f((u16)(m.y>>16));
            row[r][5] = b2f((u16)m.z); row[r][6] = b2f((u16)(m.z>>16));
            row[r][7] = b2f((u16)m.w); row[r][8] = b2f((u16)(m.w>>16));
            row[r][0] = (c8 > 0)   ? b2f(pr[-1]) : 0.f;
            row[r][9] = (c8 < 248) ? b2f(pr[8])  : 0.f;
        } else {
            #pragma unroll
            for (int j = 0; j < 10; j++) row[r][j] = 0.f;
        }
    }
    float o[8];
    #pragma unroll
    for (int i = 0; i < 8; i++){
        float a = 0.f;
        #pragma unroll
        for (int r = 0; r < 3; r++){
            a = fmaf(wc[r*3+0], row[r][i],   a);
            a = fmaf(wc[r*3+1], row[r][i+1], a);
            a = fmaf(wc[r*3+2], row[r][i+2], a);
        }
        o[i] = a;
    }
    uint4 st;
    st.x = (u32)f2b(o[0]) | ((u32)f2b(o[1])<<16);
    st.y = (u32)f2b(o[2]) | ((u32)f2b(o[3])<<16);
    st.z = (u32)f2b(o[4]) | ((u32)f2b(o[5])<<16);
    st.w = (u32)f2b(o[6]) | ((u32)f2b(o[7])<<16);
    *(uint4*)(outp + (size_t)bc*HW + h*256 + c8) = st;
}

// ---------------- attention partial sums (Gram + norms), dual-branch ----------------
#define NSL 64
struct AttnDual { const u16* q[2]; const u16* k[2]; float* sums; };
__global__ __launch_bounds__(256) void attn_part_kernel(AttnDual AD){
    int seg = blockIdx.x >> 11;
    int blk = blockIdx.x & 2047;     // B*8*NSL
    int sl = blk & (NSL-1);
    int bh = blk >> 6;               // b*8+h
    int b = bh >> 3, h = bh & 7;
    const u16* qp = AD.q[seg] + ((size_t)b*64 + h*8)*HW + sl*(HW/NSL);
    const u16* kp = AD.k[seg] + ((size_t)b*64 + h*8)*HW + sl*(HW/NSL);
    float acc[80];
    #pragma unroll
    for (int i = 0; i < 80; i++) acc[i] = 0.f;
    int n0 = threadIdx.x << 2;
    float qv[8][4], kw[8][4];
    #pragma unroll
    for (int i = 0; i < 8; i++){
        uint2 mq = *(const uint2*)(qp + (size_t)i*HW + n0);
        uint2 mk = *(const uint2*)(kp + (size_t)i*HW + n0);
        qv[i][0] = b2f((u16)(mq.x & 0xffffu)); qv[i][1] = b2f((u16)(mq.x >> 16));
        qv[i][2] = b2f((u16)(mq.y & 0xffffu)); qv[i][3] = b2f((u16)(mq.y >> 16));
        kw[i][0] = b2f((u16)(mk.x & 0xffffu)); kw[i][1] = b2f((u16)(mk.x >> 16));
        kw[i][2] = b2f((u16)(mk.y & 0xffffu)); kw[i][3] = b2f((u16)(mk.y >> 16));
    }
    #pragma unroll
    for (int i = 0; i < 8; i++){
        #pragma unroll
        for (int u = 0; u < 4; u++){
            acc[64+i] = fmaf(qv[i][u], qv[i][u], acc[64+i]);
            acc[72+i] = fmaf(kw[i][u], kw[i][u], acc[72+i]);
        }
        #pragma unroll
        for (int j = 0; j < 8; j++)
            #pragma unroll
            for (int u = 0; u < 4; u++)
                acc[i*8+j] = fmaf(qv[i][u], kw[j][u], acc[i*8+j]);
    }
    __shared__ float sred[4][80];
    int lane = threadIdx.x & 63, wv = threadIdx.x >> 6;
    #pragma unroll
    for (int t = 0; t < 80; t++){
        float r = acc[t];
        r += __shfl_down(r, 32); r += __shfl_down(r, 16); r += __shfl_down(r, 8);
        r += __shfl_down(r, 4);  r += __shfl_down(r, 2);  r += __shfl_down(r, 1);
        if (lane == 0) sred[wv][t] = r;
    }
    __syncthreads();
    if (threadIdx.x < 80){
        int t = threadIdx.x;
        atomicAdd(&AD.sums[seg*2560 + bh*80 + t], sred[0][t]+sred[1][t]+sred[2][t]+sred[3][t]);
    }
}

// ---------------- softmax + Weff = po . attn, dual-branch ----------------
struct WeffDual { const float* sums; const float* temp; const float* po[2]; u16* weff[2]; };
__global__ __launch_bounds__(64) void weff_kernel(WeffDual WD){
    int seg = blockIdx.x >> 2;
    int b = blockIdx.x & 3;
    const float* po = WD.po[seg];
    u16* weff = WD.weff[seg];
    __shared__ float at[8][8][8];
    int t = threadIdx.x;
    {
        int h = t >> 3, i = t & 7;
        const float* f = WD.sums + seg*2560 + (b*8 + h)*80;
        float iq = 1.f / fmaxf(sqrtf(f[64+i]), 1e-12f);
        float tv = WD.temp[h];
        float row[8]; float m = -1e30f;
        #pragma unroll
        for (int j = 0; j < 8; j++){
            float ik = 1.f / fmaxf(sqrtf(f[72+j]), 1e-12f);
            row[j] = f[i*8+j]*iq*ik*tv;
            m = fmaxf(m, row[j]);
        }
        float s = 0.f;
        #pragma unroll
        for (int j = 0; j < 8; j++){ row[j] = expf(row[j]-m); s += row[j]; }
        float rsv = 1.f/s;
        #pragma unroll
        for (int j = 0; j < 8; j++) at[h][i][j] = row[j]*rsv;
    }
    __syncthreads();
    int o = t;
    for (int g = 0; g < 64; g++){
        int h = g >> 3, j = g & 7;
        float wv = 0.f;
        #pragma unroll
        for (int i = 0; i < 8; i++) wv = fmaf(po[o*64 + h*8 + i], at[h][i][j], wv);
        weff[b*4096 + o*64 + g] = f2b(wv);
    }
}

// ---------------- fused modulation + final GEMM, dual-branch ----------------
// stage1: s,t-pre = lrelu(W_a . in + b)           (M=128, K=64, f32 in) -> LDS
// stage2: s,t = W_b(block-diag) . stage1 + b      -> acc2
// v' = v*(s+1)+t (reads dw'd v plane)             -> LDS rows 0..63
// stage3: out = Weff(per-batch) . v' + resid      -> f32 out
struct ModFinal {
    const float* in[2]; const u16* wa[2]; const u16* wb[2];
    const float* b0[2]; const float* b2[2]; const float* b1[2]; const float* b3[2];
    const u16* wf[2];
    const u16* v[2];
    const float* resid[2];
    float* out[2];
};
__global__ __launch_bounds__(256) void modfinal_kernel(ModFinal M){
    __shared__ u32 lds[128*65];     // stage outputs (pixel-pair swizzled)
    __shared__ u16 wl[8192];        // weight staging (chunk-swizzled)
    int seg = blockIdx.x >> 11, tile = blockIdx.x & 2047;
    int w = threadIdx.x >> 6, lane = threadIdx.x & 63;
    int quad = lane >> 4, l16 = lane & 15;
    int b = tile >> 9;
    int pbase = ((tile & 511) << 7) + (w << 5) + (l16 << 1);
    int pxp = (w << 4) + l16;

    auto loadW = [&](const u16* W, int nrows){
        for (int i = threadIdx.x; i < nrows*8; i += 256){
            int row = i >> 3, ch = i & 7;
            uint4 vv = *(const uint4*)(W + row*64 + ch*8);
            *(uint4*)(wl + row*64 + ((ch ^ (row & 7)) << 3)) = vv;
        }
    };

    // ---- stage 1 ----
    loadW(M.wa[seg], 128);
    __syncthreads();
    f4 acc[8][2];
    #pragma unroll
    for (int mi = 0; mi < 8; mi++){ acc[mi][0] = (f4){0.f,0.f,0.f,0.f}; acc[mi][1] = (f4){0.f,0.f,0.f,0.f}; }
    #pragma unroll
    for (int ks = 0; ks < 2; ks++){
        const float* pp = M.in[seg] + ((size_t)b*64 + ks*32 + quad*8)*HW + pbase;
        bh8 f0, f1;
        #pragma unroll
        for (int j = 0; j < 8; j++){
            float2 f = *(const float2*)(pp + (size_t)j*HW);
            f0[j] = (short)f2b(f.x);
            f1[j] = (short)f2b(f.y);
        }
        #pragma unroll
        for (int mi = 0; mi < 8; mi++){
            bh8 a;
            __builtin_memcpy(&a, wl + (mi*16 + l16)*64 + ((((ks<<2)+quad) ^ (l16 & 7)) << 3), 16);
            acc[mi][0] = mfma16(a, f0, acc[mi][0]);
            acc[mi][1] = mfma16(a, f1, acc[mi][1]);
        }
    }
    {
        const float* b0v = M.b0[seg]; const float* b2v = M.b2[seg];
        #pragma unroll
        for (int mi = 0; mi < 8; mi++)
        #pragma unroll
        for (int r = 0; r < 4; r++){
            int o = mi*16 + quad*4 + r;
            float bi = (o < 64) ? b0v[o] : b2v[o-64];
            float v0 = acc[mi][0][r] + bi; v0 = v0 > 0.f ? v0 : 0.1f*v0;
            float v1 = acc[mi][1][r] + bi; v1 = v1 > 0.f ? v1 : 0.1f*v1;
            lds[o*65 + ((pxp + ((o>>2)&3)*4) & 63)] = (u32)f2b(v0) | ((u32)f2b(v1) << 16);
        }
    }
    __syncthreads();

    // ---- stage 2 (block-diag) ----
    loadW(M.wb[seg], 128);
    __syncthreads();
    f4 acc2[8][2];
    #pragma unroll
    for (int mi = 0; mi < 8; mi++){ acc2[mi][0] = (f4){0.f,0.f,0.f,0.f}; acc2[mi][1] = (f4){0.f,0.f,0.f,0.f}; }
    #pragma unroll
    for (int ks = 0; ks < 4; ks++){
        int kb = ks*32 + quad*8;
        bh8 bb0, bb1;
        #pragma unroll
        for (int j = 0; j < 8; j++){
            int ch = kb + j;
            u32 m = lds[ch*65 + ((pxp + ((ch>>2)&3)*4) & 63)];
            bb0[j] = (short)(m & 0xffffu);
            bb1[j] = (short)(m >> 16);
        }
        #pragma unroll
        for (int mi = 0; mi < 8; mi++){
            if (mi < 4 ? (ks < 2) : (ks >= 2)){
                int ksl = (mi >= 4) ? ks - 2 : ks;
                bh8 a;
                __builtin_memcpy(&a, wl + (mi*16 + l16)*64 + ((((ksl<<2)+quad) ^ (l16 & 7)) << 3), 16);
                acc2[mi][0] = mfma16(a, bb0, acc2[mi][0]);
                acc2[mi][1] = mfma16(a, bb1, acc2[mi][1]);
            }
        }
    }
    __syncthreads();   // stage2 lds reads done before v' overwrite / wf load

    // ---- v' to LDS + stage-3 weight load ----
    loadW(M.wf[seg] + b*4096, 64);
    {
        const float* b1v = M.b1[seg]; const float* b3v = M.b3[seg];
        const u16* vP = M.v[seg];
        #pragma unroll
        for (int mi = 0; mi < 4; mi++)
        #pragma unroll
        for (int r = 0; r < 4; r++){
            int o = mi*16 + quad*4 + r;
            size_t pidx = ((size_t)b*64 + o)*HW + pbase;
            float s0 = acc2[mi][0][r] + b1v[o];
            float s1 = acc2[mi][1][r] + b1v[o];
            float t0 = acc2[mi+4][0][r] + b3v[o];
            float t1 = acc2[mi+4][1][r] + b3v[o];
            u32 vv = *(const u32*)(vP + pidx);
            float v0 = b2f((u16)(vv & 0xffffu)), v1 = b2f((u16)(vv >> 16));
            lds[o*65 + ((pxp + ((o>>2)&3)*4) & 63)] = (u32)f2b(v0*(s0+1.f)+t0)
                                                    | ((u32)f2b(v1*(s1+1.f)+t1) << 16);
        }
    }
    __syncthreads();

    // ---- stage 3: out = Weff . v' + resid ----
    f4 accF[4][2];
    #pragma unroll
    for (int mi = 0; mi < 4; mi++){ accF[mi][0] = (f4){0.f,0.f,0.f,0.f}; accF[mi][1] = (f4){0.f,0.f,0.f,0.f}; }
    #pragma unroll
    for (int ks = 0; ks < 2; ks++){
        int kb = ks*32 + quad*8;
        bh8 bb0, bb1;
        #pragma unroll
        for (int j = 0; j < 8; j++){
            int ch = kb + j;
            u32 m = lds[ch*65 + ((pxp + ((ch>>2)&3)*4) & 63)];
            bb0[j] = (short)(m & 0xffffu);
            bb1[j] = (short)(m >> 16);
        }
        #pragma unroll
        for (int mi = 0; mi < 4; mi++){
            bh8 a;
            __builtin_memcpy(&a, wl + (mi*16 + l16)*64 + ((((ks<<2)+quad) ^ (l16 & 7)) << 3), 16);
            accF[mi][0] = mfma16(a, bb0, accF[mi][0]);
            accF[mi][1] = mfma16(a, bb1, accF[mi][1]);
        }
    }
    {
        const float* resid = M.resid[seg];
        float* outF = M.out[seg];
        #pragma unroll
        for (int mi = 0; mi < 4; mi++)
        #pragma unroll
        for (int r = 0; r < 4; r++){
            int o = mi*16 + quad*4 + r;
            size_t pidx = ((size_t)b*64 + o)*HW + pbase;
            float2 rr = *(const float2*)(resid + pidx);
            float2 st; st.x = accF[mi][0][r] + rr.x; st.y = accF[mi][1][r] + rr.y;
            *(float2*)(outF + pidx) = st;
        }
    }
}

extern "C" void kernel_launch(void* const* d_in, const int* in_sizes, int n_in,
                              void* d_out, int out_size, void* d_ws, size_t ws_size,
                              hipStream_t stream){
    const float* x    = (const float*)d_in[0];
    const float* y    = (const float*)d_in[1];
    const float* ln_w = (const float*)d_in[2];
    const float* ln_b = (const float*)d_in[3];
    const float* temp = (const float*)d_in[4];
    const float* kv_w[2]   = {(const float*)d_in[5],  (const float*)d_in[10]};
    const float* kvdw_w[2] = {(const float*)d_in[6],  (const float*)d_in[11]};
    const float* q_w[2]    = {(const float*)d_in[7],  (const float*)d_in[12]};
    const float* qdw_w[2]  = {(const float*)d_in[8],  (const float*)d_in[13]};
    const float* po_w[2]   = {(const float*)d_in[9],  (const float*)d_in[14]};
    const float* mm_w[2]   = {(const float*)d_in[15], (const float*)d_in[17]};
    const float* mm_b[2]   = {(const float*)d_in[16], (const float*)d_in[18]};

    const size_t HPE = (size_t)BATCH*64*HW;   // elems per 64-ch plane
    u16* PL = (u16*)d_ws;                     // 9 planes
    u16* P[9];
    for (int i = 0; i < 9; i++) P[i] = PL + (size_t)i*HPE;
    float* sums = (float*)(PL + 9*HPE);       // 2 * 2560 f32
    float* lnc  = sums + 5120;                // 768 f32 LN rowsum constants
    u16* warena = (u16*)(lnc + 768);
    const int WKV[2] = {0, 8192}, WQ[2] = {16384, 20480};
    const int WMA[2] = {24576, 40960}, WMB[2] = {32768, 49152};
    const int WEFF[2] = {57344, 73728};

    size_t need = 9*HPE*2 + (5120+768)*4 + 90112*2;
    if (ws_size < need) return;

    SetupArgs S{};
    int nj = 0;
    auto add = [&](const float* s, u16* d, int n, const float* cs){ S.j[nj] = {s, d, n, cs}; nj++; };
    for (int br = 0; br < 2; br++){
        add(kv_w[br],        warena + WKV[br],        8192, ln_w);
        add(q_w[br],         warena + WQ[br],         4096, ln_w);
        add(mm_w[br],        warena + WMA[br],        4096, nullptr);  // W0 -> rows 0-63
        add(mm_w[br]+8192,   warena + WMA[br] + 4096, 4096, nullptr);  // W2 -> rows 64-127
        add(mm_w[br]+4096,   warena + WMB[br],        4096, nullptr);  // W1 -> rows 0-63
        add(mm_w[br]+12288,  warena + WMB[br] + 4096, 4096, nullptr);  // W3 -> rows 64-127
    }
    S.kvw[0] = kv_w[0]; S.kvw[1] = kv_w[1];
    S.qw[0]  = q_w[0];  S.qw[1]  = q_w[1];
    S.lnw = ln_w; S.lnb = ln_b; S.sums = sums; S.lnc = lnc;
    setup_kernel<<<17, 256, 0, stream>>>(S);

    const int GT = NPIX/128;     // 2048 gemm tiles per branch

    // kv conv both branches: br0 x -> P0(k),P1(v); br1 y -> P3(k),P4(v)
    GemmDual GK{};
    GK.in[0] = x; GK.in[1] = y;
    GK.wa[0] = warena + WKV[0]; GK.wa[1] = warena + WKV[1];
    GK.rs[0] = lnc;        GK.rb[0] = lnc + 128;
    GK.rs[1] = lnc + 256;  GK.rb[1] = lnc + 384;
    GK.outLo[0] = P[0]; GK.outHi[0] = P[1];
    GK.outLo[1] = P[3]; GK.outHi[1] = P[4];
    gemmln_kernel<8><<<2*GT, 256, 0, stream>>>(GK);

    // q conv both branches: br0 y -> P2; br1 x -> P5
    GemmDual GQ{};
    GQ.in[0] = y; GQ.in[1] = x;
    GQ.wa[0] = warena + WQ[0]; GQ.wa[1] = warena + WQ[1];
    GQ.rs[0] = lnc + 512;  GQ.rb[0] = lnc + 576;
    GQ.rs[1] = lnc + 640;  GQ.rb[1] = lnc + 704;
    GQ.outLo[0] = P[2]; GQ.outHi[0] = P[2];
    GQ.outLo[1] = P[5]; GQ.outHi[1] = P[5];
    gemmln_kernel<4><<<2*GT, 256, 0, stream>>>(GQ);

    // depthwise br0: P0->P6 (k), P1->P7 (v), P2->P8 (q)
    DwArgs D0{P[0], P[1], P[2], P[6], P[7], P[8],
              kvdw_w[0], kvdw_w[0], qdw_w[0], 0, 64, 0};
    dw3_kernel<<<3*8192, 256, 0, stream>>>(D0);
    // depthwise br1: P3->P0 (k), P4->P1 (v), P5->P2 (q)  (overwrites dead br0 inputs)
    DwArgs D1{P[3], P[4], P[5], P[0], P[1], P[2],
              kvdw_w[1], kvdw_w[1], qdw_w[1], 0, 64, 0};
    dw3_kernel<<<3*8192, 256, 0, stream>>>(D1);

    // attention stats both branches
    AttnDual AD{};
    AD.q[0] = P[8]; AD.k[0] = P[6];
    AD.q[1] = P[2]; AD.k[1] = P[0];
    AD.sums = sums;
    attn_part_kernel<<<2*BATCH*8*NSL, 256, 0, stream>>>(AD);

    // softmax + Weff both branches
    WeffDual WD{};
    WD.sums = sums; WD.temp = temp;
    WD.po[0] = po_w[0]; WD.po[1] = po_w[1];
    WD.weff[0] = warena + WEFF[0]; WD.weff[1] = warena + WEFF[1];
    weff_kernel<<<2*BATCH, 64, 0, stream>>>(WD);

    // fused modulation + final both branches
    float* outp = (float*)d_out;
    ModFinal M{};
    M.in[0] = x; M.in[1] = y;
    M.wa[0] = warena + WMA[0]; M.wa[1] = warena + WMA[1];
    M.wb[0] = warena + WMB[0]; M.wb[1] = warena + WMB[1];
    M.b0[0] = mm_b[0];       M.b0[1] = mm_b[1];
    M.b2[0] = mm_b[0] + 128; M.b2[1] = mm_b[1] + 128;
    M.b1[0] = mm_b[0] + 64;  M.b1[1] = mm_b[1] + 64;
    M.b3[0] = mm_b[0] + 192; M.b3[1] = mm_b[1] + 192;
    M.wf[0] = warena + WEFF[0]; M.wf[1] = warena + WEFF[1];
    M.v[0] = P[7]; M.v[1] = P[1];
    M.resid[0] = y; M.resid[1] = x;
    M.out[0] = outp; M.out[1] = outp + HPE;
    modfinal_kernel<<<2*GT, 256, 0, stream>>>(M);
}

// Round 4
// 721.417 us; speedup vs baseline: 1.2263x; 1.0279x over previous
//
#include <hip/hip_runtime.h>
#include <hip/hip_bf16.h>

#define HW 65536
#define BATCH 4
#define NPIX (BATCH*HW)   // 262144 pixels

typedef unsigned short u16;
typedef unsigned int   u32;
typedef __attribute__((ext_vector_type(8))) short bh8;   // 8 bf16 (A/B frag, 4 VGPRs)
typedef __attribute__((ext_vector_type(4))) float f4;    // 4 f32 (C/D frag)

__device__ __forceinline__ float b2f(u16 u){
    u32 i = ((u32)u) << 16; float f; __builtin_memcpy(&f, &i, 4); return f;
}
__device__ __forceinline__ u16 f2b(float f){
    __hip_bfloat16 h = __float2bfloat16(f); u16 u; __builtin_memcpy(&u, &h, 2); return u;
}

__device__ __forceinline__ f4 mfma16(bh8 a, bh8 b, f4 c){
    return __builtin_amdgcn_mfma_f32_16x16x32_bf16(a, b, c, 0, 0, 0);
}

// ---------------- setup: weight cvt + LN rowsums + zero sums, one dispatch ----------------
struct CvtJob { const float* src; u16* dst; int n; const float* cs; };
struct SetupArgs {
    CvtJob j[12];
    const float* kvw[2]; const float* qw[2];
    const float* lnw; const float* lnb;
    float* sums; float* lnc;
};
__global__ __launch_bounds__(256) void setup_kernel(SetupArgs S){
    int blk = blockIdx.x;
    if (blk < 12){
        const CvtJob J = S.j[blk];
        if (J.cs){
            for (int i = threadIdx.x; i < J.n; i += 256) J.dst[i] = f2b(J.src[i] * J.cs[i & 63]);
        } else {
            for (int i = threadIdx.x; i < J.n; i += 256) J.dst[i] = f2b(J.src[i]);
        }
        return;
    }
    int pb = blk - 12;
    if (pb == 0){
        for (int i = threadIdx.x; i < 5120; i += 256) S.sums[i] = 0.f;
    } else if (pb <= 2){
        const float* W = S.kvw[pb-1];
        float* rs = S.lnc + (pb-1)*256;
        int o = threadIdx.x;
        if (o < 128){
            float a = 0.f, bb = 0.f;
            for (int c = 0; c < 64; c++){
                float wv = W[o*64 + c];
                a = fmaf(wv, S.lnw[c], a); bb = fmaf(wv, S.lnb[c], bb);
            }
            rs[o] = a; rs[128 + o] = bb;
        }
    } else {
        const float* W = S.qw[pb-3];
        float* rs = S.lnc + 512 + (pb-3)*128;
        int o = threadIdx.x;
        if (o < 64){
            float a = 0.f, bb = 0.f;
            for (int c = 0; c < 64; c++){
                float wv = W[o*64 + c];
                a = fmaf(wv, S.lnw[c], a); bb = fmaf(wv, S.lnb[c], bb);
            }
            rs[o] = a; rs[64 + o] = bb;
        }
    }
}

// ---------------- LN-folded 1x1 conv GEMM, dual-branch, LDS-staged weights ----------------
// out = inv*(Wl.x - mu*rs[o]) + rb[o]; weights pre-scaled by ln_w.
// Input loads hoisted BEFORE the weight-staging barrier (latency hidden).
struct GemmDual {
    const float* in[2];
    const u16* wa[2];
    const float* rs[2]; const float* rb[2];
    u16* outLo[2]; u16* outHi[2];
};
template<int MT>
__global__ __launch_bounds__(256,4) void gemmln_kernel(GemmDual G){
    constexpr int KD = 64;
    constexpr int NW = MT*16*KD;
    __shared__ u16 wl[NW];
    int seg = blockIdx.x >> 11, tile = blockIdx.x & 2047;
    int w = threadIdx.x >> 6, lane = threadIdx.x & 63;
    int quad = lane >> 4, l16 = lane & 15;
    int b = tile >> 9;
    int pbase = ((tile & 511) << 7) + (w << 5) + (l16 << 1);

    // ---- input loads first: 16 float2, all in flight during weight staging ----
    const float* in = G.in[seg];
    float2 f[16];
    #pragma unroll
    for (int ks = 0; ks < 2; ks++)
        #pragma unroll
        for (int j = 0; j < 8; j++)
            f[ks*8+j] = *(const float2*)(in + ((size_t)b*64 + ks*32 + quad*8 + j)*HW + pbase);

    // ---- weight staging (chunk-swizzled: 2-way banks on frag reads) ----
    {
        const u16* W = G.wa[seg];
        for (int i = threadIdx.x; i < NW/8; i += 256){
            int row = i >> 3, ch = i & 7;
            uint4 v = *(const uint4*)(W + row*KD + ch*8);
            *(uint4*)(wl + row*KD + ((ch ^ (row & 7)) << 3)) = v;
        }
    }
    __syncthreads();

    // ---- stats + convert ----
    float s1a = 0.f, s2a = 0.f, s1b = 0.f, s2b = 0.f;
    bh8 b0[2], b1[2];
    #pragma unroll
    for (int ks = 0; ks < 2; ks++)
        #pragma unroll
        for (int j = 0; j < 8; j++){
            float2 fv = f[ks*8+j];
            s1a += fv.x; s2a = fmaf(fv.x, fv.x, s2a);
            s1b += fv.y; s2b = fmaf(fv.y, fv.y, s2b);
            b0[ks][j] = (short)f2b(fv.x);
            b1[ks][j] = (short)f2b(fv.y);
        }

    f4 acc[MT][2];
    #pragma unroll
    for (int mi = 0; mi < MT; mi++){ acc[mi][0] = (f4){0.f,0.f,0.f,0.f}; acc[mi][1] = (f4){0.f,0.f,0.f,0.f}; }
    #pragma unroll
    for (int ks = 0; ks < 2; ks++)
        #pragma unroll
        for (int mi = 0; mi < MT; mi++){
            bh8 a;
            __builtin_memcpy(&a, wl + (mi*16 + l16)*KD + ((((ks<<2)+quad) ^ (l16 & 7)) << 3), 16);
            acc[mi][0] = mfma16(a, b0[ks], acc[mi][0]);
            acc[mi][1] = mfma16(a, b1[ks], acc[mi][1]);
        }

    s1a += __shfl_xor(s1a, 16); s1a += __shfl_xor(s1a, 32);
    s2a += __shfl_xor(s2a, 16); s2a += __shfl_xor(s2a, 32);
    s1b += __shfl_xor(s1b, 16); s1b += __shfl_xor(s1b, 32);
    s2b += __shfl_xor(s2b, 16); s2b += __shfl_xor(s2b, 32);
    float mu0 = s1a*(1.f/64.f), iv0 = rsqrtf(s2a*(1.f/64.f) - mu0*mu0 + 1e-5f);
    float mu1 = s1b*(1.f/64.f), iv1 = rsqrtf(s2b*(1.f/64.f) - mu1*mu1 + 1e-5f);

    const float* rs = G.rs[seg]; const float* rb = G.rb[seg];
    u16* oLo = G.outLo[seg]; u16* oHi = G.outHi[seg];
    #pragma unroll
    for (int mi = 0; mi < MT; mi++)
    #pragma unroll
    for (int r = 0; r < 4; r++){
        int o = mi*16 + quad*4 + r;
        size_t pidx = ((size_t)b*64 + (o & 63))*HW + pbase;
        float rsv = rs[o], rbv = rb[o];
        float va0 = iv0*(acc[mi][0][r] - mu0*rsv) + rbv;
        float va1 = iv1*(acc[mi][1][r] - mu1*rsv) + rbv;
        u16* dst = (o < 64) ? oLo : oHi;
        *(u32*)(dst + pidx) = (u32)f2b(va0) | ((u32)f2b(va1) << 16);
    }
}

// ---------------- depthwise 3x3, 6 planes in ONE dispatch, 8 px/thread ----------------
struct Dw6 { const u16* in[6]; u16* out[6]; const float* w[6]; int choff[6]; };
__global__ __launch_bounds__(256) void dw6_kernel(Dw6 A){
    int seg = blockIdx.x >> 13;                  // 6 segs x 8192 blocks
    int lid = ((blockIdx.x & 8191) << 8) + threadIdx.x;
    const u16* inp = A.in[seg];
    u16* outp      = A.out[seg];
    const float* wd = A.w[seg];
    int choff      = A.choff[seg];
    int bc = lid >> 13;
    int n8 = lid & 8191;
    int h = n8 >> 5, c8 = (n8 & 31) << 3;
    const float* wc = wd + ((size_t)((bc & 63) + choff))*9;
    const u16* p = inp + (size_t)bc*HW;
    float row[3][10];
    #pragma unroll
    for (int r = 0; r < 3; r++){
        int hh = h - 1 + r;
        bool ok = (unsigned)hh < 256u;
        const u16* pr = p + hh*256 + c8;
        if (ok){
            uint4 m = *(const uint4*)pr;
            row[r][1] = b2f((u16)m.x); row[r][2] = b2f((u16)(m.x>>16));
            row[r][3] = b2f((u16)m.y); row[r][4] = b2f((u16)(m.y>>16));
            row[r][5] = b2f((u16)m.z); row[r][6] = b2f((u16)(m.z>>16));
            row[r][7] = b2f((u16)m.w); row[r][8] = b2f((u16)(m.w>>16));
            row[r][0] = (c8 > 0)   ? b2f(pr[-1]) : 0.f;
            row[r][9] = (c8 < 248) ? b2f(pr[8])  : 0.f;
        } else {
            #pragma unroll
            for (int j = 0; j < 10; j++) row[r][j] = 0.f;
        }
    }
    float o[8];
    #pragma unroll
    for (int i = 0; i < 8; i++){
        float a = 0.f;
        #pragma unroll
        for (int r = 0; r < 3; r++){
            a = fmaf(wc[r*3+0], row[r][i],   a);
            a = fmaf(wc[r*3+1], row[r][i+1], a);
            a = fmaf(wc[r*3+2], row[r][i+2], a);
        }
        o[i] = a;
    }
    uint4 st;
    st.x = (u32)f2b(o[0]) | ((u32)f2b(o[1])<<16);
    st.y = (u32)f2b(o[2]) | ((u32)f2b(o[3])<<16);
    st.z = (u32)f2b(o[4]) | ((u32)f2b(o[5])<<16);
    st.w = (u32)f2b(o[6]) | ((u32)f2b(o[7])<<16);
    *(uint4*)(outp + (size_t)bc*HW + h*256 + c8) = st;
}

// ---------------- attention partial sums (Gram + norms), dual-branch ----------------
#define NSL 64
struct AttnDual { const u16* q[2]; const u16* k[2]; float* sums; };
__global__ __launch_bounds__(256) void attn_part_kernel(AttnDual AD){
    int seg = blockIdx.x >> 11;
    int blk = blockIdx.x & 2047;     // B*8*NSL
    int sl = blk & (NSL-1);
    int bh = blk >> 6;               // b*8+h
    int b = bh >> 3, h = bh & 7;
    const u16* qp = AD.q[seg] + ((size_t)b*64 + h*8)*HW + sl*(HW/NSL);
    const u16* kp = AD.k[seg] + ((size_t)b*64 + h*8)*HW + sl*(HW/NSL);
    float acc[80];
    #pragma unroll
    for (int i = 0; i < 80; i++) acc[i] = 0.f;
    int n0 = threadIdx.x << 2;
    float qv[8][4], kw[8][4];
    #pragma unroll
    for (int i = 0; i < 8; i++){
        uint2 mq = *(const uint2*)(qp + (size_t)i*HW + n0);
        uint2 mk = *(const uint2*)(kp + (size_t)i*HW + n0);
        qv[i][0] = b2f((u16)(mq.x & 0xffffu)); qv[i][1] = b2f((u16)(mq.x >> 16));
        qv[i][2] = b2f((u16)(mq.y & 0xffffu)); qv[i][3] = b2f((u16)(mq.y >> 16));
        kw[i][0] = b2f((u16)(mk.x & 0xffffu)); kw[i][1] = b2f((u16)(mk.x >> 16));
        kw[i][2] = b2f((u16)(mk.y & 0xffffu)); kw[i][3] = b2f((u16)(mk.y >> 16));
    }
    #pragma unroll
    for (int i = 0; i < 8; i++){
        #pragma unroll
        for (int u = 0; u < 4; u++){
            acc[64+i] = fmaf(qv[i][u], qv[i][u], acc[64+i]);
            acc[72+i] = fmaf(kw[i][u], kw[i][u], acc[72+i]);
        }
        #pragma unroll
        for (int j = 0; j < 8; j++)
            #pragma unroll
            for (int u = 0; u < 4; u++)
                acc[i*8+j] = fmaf(qv[i][u], kw[j][u], acc[i*8+j]);
    }
    __shared__ float sred[4][80];
    int lane = threadIdx.x & 63, wv = threadIdx.x >> 6;
    #pragma unroll
    for (int t = 0; t < 80; t++){
        float r = acc[t];
        r += __shfl_down(r, 32); r += __shfl_down(r, 16); r += __shfl_down(r, 8);
        r += __shfl_down(r, 4);  r += __shfl_down(r, 2);  r += __shfl_down(r, 1);
        if (lane == 0) sred[wv][t] = r;
    }
    __syncthreads();
    if (threadIdx.x < 80){
        int t = threadIdx.x;
        atomicAdd(&AD.sums[seg*2560 + bh*80 + t], sred[0][t]+sred[1][t]+sred[2][t]+sred[3][t]);
    }
}

// ---------------- softmax + Weff = po . attn, dual-branch ----------------
struct WeffDual { const float* sums; const float* temp; const float* po[2]; u16* weff[2]; };
__global__ __launch_bounds__(64) void weff_kernel(WeffDual WD){
    int seg = blockIdx.x >> 2;
    int b = blockIdx.x & 3;
    const float* po = WD.po[seg];
    u16* weff = WD.weff[seg];
    __shared__ float at[8][8][8];
    int t = threadIdx.x;
    {
        int h = t >> 3, i = t & 7;
        const float* f = WD.sums + seg*2560 + (b*8 + h)*80;
        float iq = 1.f / fmaxf(sqrtf(f[64+i]), 1e-12f);
        float tv = WD.temp[h];
        float row[8]; float m = -1e30f;
        #pragma unroll
        for (int j = 0; j < 8; j++){
            float ik = 1.f / fmaxf(sqrtf(f[72+j]), 1e-12f);
            row[j] = f[i*8+j]*iq*ik*tv;
            m = fmaxf(m, row[j]);
        }
        float s = 0.f;
        #pragma unroll
        for (int j = 0; j < 8; j++){ row[j] = expf(row[j]-m); s += row[j]; }
        float rsv = 1.f/s;
        #pragma unroll
        for (int j = 0; j < 8; j++) at[h][i][j] = row[j]*rsv;
    }
    __syncthreads();
    int o = t;
    for (int g = 0; g < 64; g++){
        int h = g >> 3, j = g & 7;
        float wv = 0.f;
        #pragma unroll
        for (int i = 0; i < 8; i++) wv = fmaf(po[o*64 + h*8 + i], at[h][i][j], wv);
        weff[b*4096 + o*64 + g] = f2b(wv);
    }
}

// ---------------- fused modulation + final GEMM, dual-branch ----------------
// LDS = pixel buffer only (32768 B -> 4 blocks/CU); weights direct from global.
// v prefetched after stage1 MFMAs; resid prefetched before stage-3 barrier.
// Row layout: lds[o*64 + ((pxp + ((o>>2)&3)*8) & 63)] -> 2-way banks all phases.
struct ModFinal {
    const float* in[2]; const u16* wa[2]; const u16* wb[2];
    const float* b0[2]; const float* b2[2]; const float* b1[2]; const float* b3[2];
    const u16* wf[2];
    const u16* v[2];
    const float* resid[2];
    float* out[2];
};
__global__ __launch_bounds__(256,4) void modfinal_kernel(ModFinal M){
    __shared__ u32 lds[128*64];
    int seg = blockIdx.x >> 11, tile = blockIdx.x & 2047;
    int w = threadIdx.x >> 6, lane = threadIdx.x & 63;
    int quad = lane >> 4, l16 = lane & 15;
    int b = tile >> 9;
    int pbase = ((tile & 511) << 7) + (w << 5) + (l16 << 1);
    int pxp = (w << 4) + l16;

    const float* in = M.in[seg];
    const u16* wa = M.wa[seg];

    // ---- stage 1 (pipelined input loads) ----
    float2 f[8];
    #pragma unroll
    for (int j = 0; j < 8; j++)
        f[j] = *(const float2*)(in + ((size_t)b*64 + quad*8 + j)*HW + pbase);

    f4 acc[8][2];
    #pragma unroll
    for (int mi = 0; mi < 8; mi++){ acc[mi][0] = (f4){0.f,0.f,0.f,0.f}; acc[mi][1] = (f4){0.f,0.f,0.f,0.f}; }

    #pragma unroll
    for (int ks = 0; ks < 2; ks++){
        float2 fn[8];
        if (ks == 0){
            #pragma unroll
            for (int j = 0; j < 8; j++)
                fn[j] = *(const float2*)(in + ((size_t)b*64 + 32 + quad*8 + j)*HW + pbase);
        }
        bh8 f0, f1;
        #pragma unroll
        for (int j = 0; j < 8; j++){
            f0[j] = (short)f2b(f[j].x);
            f1[j] = (short)f2b(f[j].y);
        }
        #pragma unroll
        for (int mi = 0; mi < 8; mi++){
            bh8 a;
            __builtin_memcpy(&a, wa + (mi*16 + l16)*64 + ks*32 + quad*8, 16);
            acc[mi][0] = mfma16(a, f0, acc[mi][0]);
            acc[mi][1] = mfma16(a, f1, acc[mi][1]);
        }
        #pragma unroll
        for (int j = 0; j < 8; j++) f[j] = fn[j];
    }

    // ---- v prefetch: in flight across stage-1 epilogue + barrier + stage 2 ----
    u32 vpref[16];
    {
        const u16* vP = M.v[seg];
        #pragma unroll
        for (int mi = 0; mi < 4; mi++)
        #pragma unroll
        for (int r = 0; r < 4; r++)
            vpref[mi*4+r] = *(const u32*)(vP + ((size_t)b*64 + mi*16 + quad*4 + r)*HW + pbase);
    }

    // ---- stage-1 epilogue: bias + lrelu -> LDS ----
    {
        const float* b0v = M.b0[seg]; const float* b2v = M.b2[seg];
        #pragma unroll
        for (int mi = 0; mi < 8; mi++)
        #pragma unroll
        for (int r = 0; r < 4; r++){
            int o = mi*16 + quad*4 + r;
            float bi = (o < 64) ? b0v[o] : b2v[o-64];
            float v0 = acc[mi][0][r] + bi; v0 = v0 > 0.f ? v0 : 0.1f*v0;
            float v1 = acc[mi][1][r] + bi; v1 = v1 > 0.f ? v1 : 0.1f*v1;
            lds[o*64 + ((pxp + ((o>>2)&3)*8) & 63)] = (u32)f2b(v0) | ((u32)f2b(v1) << 16);
        }
    }
    __syncthreads();

    // ---- stage 2 (block-diag K=128) ----
    const u16* wb = M.wb[seg];
    f4 acc2[8][2];
    #pragma unroll
    for (int mi = 0; mi < 8; mi++){ acc2[mi][0] = (f4){0.f,0.f,0.f,0.f}; acc2[mi][1] = (f4){0.f,0.f,0.f,0.f}; }
    #pragma unroll
    for (int ks = 0; ks < 4; ks++){
        int kb = ks*32 + quad*8;
        bh8 bb0, bb1;
        #pragma unroll
        for (int j = 0; j < 8; j++){
            int ch = kb + j;
            u32 m = lds[ch*64 + ((pxp + ((ch>>2)&3)*8) & 63)];
            bb0[j] = (short)(m & 0xffffu);
            bb1[j] = (short)(m >> 16);
        }
        #pragma unroll
        for (int mi = 0; mi < 8; mi++){
            if (mi < 4 ? (ks < 2) : (ks >= 2)){
                int ksl = (mi >= 4) ? ks - 2 : ks;
                bh8 a;
                __builtin_memcpy(&a, wb + (mi*16 + l16)*64 + ksl*32 + quad*8, 16);
                acc2[mi][0] = mfma16(a, bb0, acc2[mi][0]);
                acc2[mi][1] = mfma16(a, bb1, acc2[mi][1]);
            }
        }
    }
    __syncthreads();   // stage-2 reads done before v' overwrite

    // ---- vmod: v' = v*(s+1)+t -> LDS rows 0..63 ----
    {
        const float* b1v = M.b1[seg]; const float* b3v = M.b3[seg];
        #pragma unroll
        for (int mi = 0; mi < 4; mi++)
        #pragma unroll
        for (int r = 0; r < 4; r++){
            int o = mi*16 + quad*4 + r;
            float s0 = acc2[mi][0][r] + b1v[o];
            float s1 = acc2[mi][1][r] + b1v[o];
            float t0 = acc2[mi+4][0][r] + b3v[o];
            float t1 = acc2[mi+4][1][r] + b3v[o];
            u32 vv = vpref[mi*4+r];
            float v0 = b2f((u16)(vv & 0xffffu)), v1 = b2f((u16)(vv >> 16));
            lds[o*64 + ((pxp + ((o>>2)&3)*8) & 63)] = (u32)f2b(v0*(s0+1.f)+t0)
                                                    | ((u32)f2b(v1*(s1+1.f)+t1) << 16);
        }
    }
    // ---- resid prefetch: in flight across barrier + stage 3 ----
    float2 rpre[16];
    {
        const float* resid = M.resid[seg];
        #pragma unroll
        for (int mi = 0; mi < 4; mi++)
        #pragma unroll
        for (int r = 0; r < 4; r++)
            rpre[mi*4+r] = *(const float2*)(resid + ((size_t)b*64 + mi*16 + quad*4 + r)*HW + pbase);
    }
    __syncthreads();

    // ---- stage 3: out = Weff . v' + resid ----
    const u16* wf = M.wf[seg] + b*4096;
    f4 accF[4][2];
    #pragma unroll
    for (int mi = 0; mi < 4; mi++){ accF[mi][0] = (f4){0.f,0.f,0.f,0.f}; accF[mi][1] = (f4){0.f,0.f,0.f,0.f}; }
    #pragma unroll
    for (int ks = 0; ks < 2; ks++){
        int kb = ks*32 + quad*8;
        bh8 bb0, bb1;
        #pragma unroll
        for (int j = 0; j < 8; j++){
            int ch = kb + j;
            u32 m = lds[ch*64 + ((pxp + ((ch>>2)&3)*8) & 63)];
            bb0[j] = (short)(m & 0xffffu);
            bb1[j] = (short)(m >> 16);
        }
        #pragma unroll
        for (int mi = 0; mi < 4; mi++){
            bh8 a;
            __builtin_memcpy(&a, wf + (mi*16 + l16)*64 + ks*32 + quad*8, 16);
            accF[mi][0] = mfma16(a, bb0, accF[mi][0]);
            accF[mi][1] = mfma16(a, bb1, accF[mi][1]);
        }
    }
    {
        float* outF = M.out[seg];
        #pragma unroll
        for (int mi = 0; mi < 4; mi++)
        #pragma unroll
        for (int r = 0; r < 4; r++){
            int o = mi*16 + quad*4 + r;
            size_t pidx = ((size_t)b*64 + o)*HW + pbase;
            float2 rr = rpre[mi*4+r];
            float2 st; st.x = accF[mi][0][r] + rr.x; st.y = accF[mi][1][r] + rr.y;
            *(float2*)(outF + pidx) = st;
        }
    }
}

extern "C" void kernel_launch(void* const* d_in, const int* in_sizes, int n_in,
                              void* d_out, int out_size, void* d_ws, size_t ws_size,
                              hipStream_t stream){
    const float* x    = (const float*)d_in[0];
    const float* y    = (const float*)d_in[1];
    const float* ln_w = (const float*)d_in[2];
    const float* ln_b = (const float*)d_in[3];
    const float* temp = (const float*)d_in[4];
    const float* kv_w[2]   = {(const float*)d_in[5],  (const float*)d_in[10]};
    const float* kvdw_w[2] = {(const float*)d_in[6],  (const float*)d_in[11]};
    const float* q_w[2]    = {(const float*)d_in[7],  (const float*)d_in[12]};
    const float* qdw_w[2]  = {(const float*)d_in[8],  (const float*)d_in[13]};
    const float* po_w[2]   = {(const float*)d_in[9],  (const float*)d_in[14]};
    const float* mm_w[2]   = {(const float*)d_in[15], (const float*)d_in[17]};
    const float* mm_b[2]   = {(const float*)d_in[16], (const float*)d_in[18]};

    const size_t HPE = (size_t)BATCH*64*HW;   // elems per 64-ch plane
    u16* PL = (u16*)d_ws;                     // 12 planes
    u16* P[12];
    for (int i = 0; i < 12; i++) P[i] = PL + (size_t)i*HPE;
    float* sums = (float*)(PL + 12*HPE);      // 2 * 2560 f32
    float* lnc  = sums + 5120;                // 768 f32 LN rowsum constants
    u16* warena = (u16*)(lnc + 768);
    const int WKV[2] = {0, 8192}, WQ[2] = {16384, 20480};
    const int WMA[2] = {24576, 40960}, WMB[2] = {32768, 49152};
    const int WEFF[2] = {57344, 73728};

    size_t need = 12*HPE*2 + (5120+768)*4 + 90112*2;
    if (ws_size < need) return;

    SetupArgs S{};
    int nj = 0;
    auto add = [&](const float* s, u16* d, int n, const float* cs){ S.j[nj] = {s, d, n, cs}; nj++; };
    for (int br = 0; br < 2; br++){
        add(kv_w[br],        warena + WKV[br],        8192, ln_w);
        add(q_w[br],         warena + WQ[br],         4096, ln_w);
        add(mm_w[br],        warena + WMA[br],        4096, nullptr);  // W0 -> rows 0-63
        add(mm_w[br]+8192,   warena + WMA[br] + 4096, 4096, nullptr);  // W2 -> rows 64-127
        add(mm_w[br]+4096,   warena + WMB[br],        4096, nullptr);  // W1 -> rows 0-63
        add(mm_w[br]+12288,  warena + WMB[br] + 4096, 4096, nullptr);  // W3 -> rows 64-127
    }
    S.kvw[0] = kv_w[0]; S.kvw[1] = kv_w[1];
    S.qw[0]  = q_w[0];  S.qw[1]  = q_w[1];
    S.lnw = ln_w; S.lnb = ln_b; S.sums = sums; S.lnc = lnc;
    setup_kernel<<<17, 256, 0, stream>>>(S);

    const int GT = NPIX/128;     // 2048 gemm tiles per branch

    // kv conv both branches: br0 x -> P0(k),P1(v); br1 y -> P2(k),P3(v)
    GemmDual GK{};
    GK.in[0] = x; GK.in[1] = y;
    GK.wa[0] = warena + WKV[0]; GK.wa[1] = warena + WKV[1];
    GK.rs[0] = lnc;        GK.rb[0] = lnc + 128;
    GK.rs[1] = lnc + 256;  GK.rb[1] = lnc + 384;
    GK.outLo[0] = P[0]; GK.outHi[0] = P[1];
    GK.outLo[1] = P[2]; GK.outHi[1] = P[3];
    gemmln_kernel<8><<<2*GT, 256, 0, stream>>>(GK);

    // q conv both branches: br0 y -> P4; br1 x -> P5
    GemmDual GQ{};
    GQ.in[0] = y; GQ.in[1] = x;
    GQ.wa[0] = warena + WQ[0]; GQ.wa[1] = warena + WQ[1];
    GQ.rs[0] = lnc + 512;  GQ.rb[0] = lnc + 576;
    GQ.rs[1] = lnc + 640;  GQ.rb[1] = lnc + 704;
    GQ.outLo[0] = P[4]; GQ.outHi[0] = P[4];
    GQ.outLo[1] = P[5]; GQ.outHi[1] = P[5];
    gemmln_kernel<4><<<2*GT, 256, 0, stream>>>(GQ);

    // depthwise, all 6 planes in one dispatch:
    // br0: P0->P6 (k), P1->P7 (v), P4->P8 (q); br1: P2->P9, P3->P10, P5->P11
    Dw6 D{};
    D.in[0] = P[0];  D.out[0] = P[6];  D.w[0] = kvdw_w[0]; D.choff[0] = 0;
    D.in[1] = P[1];  D.out[1] = P[7];  D.w[1] = kvdw_w[0]; D.choff[1] = 64;
    D.in[2] = P[4];  D.out[2] = P[8];  D.w[2] = qdw_w[0];  D.choff[2] = 0;
    D.in[3] = P[2];  D.out[3] = P[9];  D.w[3] = kvdw_w[1]; D.choff[3] = 0;
    D.in[4] = P[3];  D.out[4] = P[10]; D.w[4] = kvdw_w[1]; D.choff[4] = 64;
    D.in[5] = P[5];  D.out[5] = P[11]; D.w[5] = qdw_w[1];  D.choff[5] = 0;
    dw6_kernel<<<6*8192, 256, 0, stream>>>(D);

    // attention stats both branches
    AttnDual AD{};
    AD.q[0] = P[8];  AD.k[0] = P[6];
    AD.q[1] = P[11]; AD.k[1] = P[9];
    AD.sums = sums;
    attn_part_kernel<<<2*BATCH*8*NSL, 256, 0, stream>>>(AD);

    // softmax + Weff both branches
    WeffDual WD{};
    WD.sums = sums; WD.temp = temp;
    WD.po[0] = po_w[0]; WD.po[1] = po_w[1];
    WD.weff[0] = warena + WEFF[0]; WD.weff[1] = warena + WEFF[1];
    weff_kernel<<<2*BATCH, 64, 0, stream>>>(WD);

    // fused modulation + final both branches
    float* outp = (float*)d_out;
    ModFinal M{};
    M.in[0] = x; M.in[1] = y;
    M.wa[0] = warena + WMA[0]; M.wa[1] = warena + WMA[1];
    M.wb[0] = warena + WMB[0]; M.wb[1] = warena + WMB[1];
    M.b0[0] = mm_b[0];       M.b0[1] = mm_b[1];
    M.b2[0] = mm_b[0] + 128; M.b2[1] = mm_b[1] + 128;
    M.b1[0] = mm_b[0] + 64;  M.b1[1] = mm_b[1] + 64;
    M.b3[0] = mm_b[0] + 192; M.b3[1] = mm_b[1] + 192;
    M.wf[0] = warena + WEFF[0]; M.wf[1] = warena + WEFF[1];
    M.v[0] = P[7]; M.v[1] = P[10];
    M.resid[0] = y; M.resid[1] = x;
    M.out[0] = outp; M.out[1] = outp + HPE;
    modfinal_kernel<<<2*GT, 256, 0, stream>>>(M);
}

// Round 5
// 694.814 us; speedup vs baseline: 1.2733x; 1.0383x over previous
//
#include <hip/hip_runtime.h>
#include <hip/hip_bf16.h>

#define HW 65536
#define BATCH 4
#define NPIX (BATCH*HW)   // 262144 pixels

typedef unsigned short u16;
typedef unsigned int   u32;
typedef __attribute__((ext_vector_type(8))) short bh8;   // 8 bf16 (A/B frag, 4 VGPRs)
typedef __attribute__((ext_vector_type(4))) float f4;    // 4 f32 (C/D frag)

__device__ __forceinline__ float b2f(u16 u){
    u32 i = ((u32)u) << 16; float f; __builtin_memcpy(&f, &i, 4); return f;
}
__device__ __forceinline__ u16 f2b(float f){
    __hip_bfloat16 h = __float2bfloat16(f); u16 u; __builtin_memcpy(&u, &h, 2); return u;
}

__device__ __forceinline__ f4 mfma16(bh8 a, bh8 b, f4 c){
    return __builtin_amdgcn_mfma_f32_16x16x32_bf16(a, b, c, 0, 0, 0);
}

// ---------------- setup: weight cvt + LN rowsums + zero sums, one dispatch ----------------
struct CvtJob { const float* src; u16* dst; int n; const float* cs; };
struct SetupArgs {
    CvtJob j[12];
    const float* kvw[2]; const float* qw[2];
    const float* lnw; const float* lnb;
    float* sums; float* lnc;
};
__global__ __launch_bounds__(256) void setup_kernel(SetupArgs S){
    int blk = blockIdx.x;
    if (blk < 12){
        const CvtJob J = S.j[blk];
        if (J.cs){
            for (int i = threadIdx.x; i < J.n; i += 256) J.dst[i] = f2b(J.src[i] * J.cs[i & 63]);
        } else {
            for (int i = threadIdx.x; i < J.n; i += 256) J.dst[i] = f2b(J.src[i]);
        }
        return;
    }
    int pb = blk - 12;
    if (pb == 0){
        for (int i = threadIdx.x; i < 5120; i += 256) S.sums[i] = 0.f;
    } else if (pb <= 2){
        const float* W = S.kvw[pb-1];
        float* rs = S.lnc + (pb-1)*256;
        int o = threadIdx.x;
        if (o < 128){
            float a = 0.f, bb = 0.f;
            for (int c = 0; c < 64; c++){
                float wv = W[o*64 + c];
                a = fmaf(wv, S.lnw[c], a); bb = fmaf(wv, S.lnb[c], bb);
            }
            rs[o] = a; rs[128 + o] = bb;
        }
    } else {
        const float* W = S.qw[pb-3];
        float* rs = S.lnc + 512 + (pb-3)*128;
        int o = threadIdx.x;
        if (o < 64){
            float a = 0.f, bb = 0.f;
            for (int c = 0; c < 64; c++){
                float wv = W[o*64 + c];
                a = fmaf(wv, S.lnw[c], a); bb = fmaf(wv, S.lnb[c], bb);
            }
            rs[o] = a; rs[64 + o] = bb;
        }
    }
}

// ---------------- LN-folded 1x1 conv GEMM, dual-branch, 4 px/lane (float4 streams) ----------------
// out = inv*(Wl.x - mu*rs[o]) + rb[o]; weights pre-scaled by ln_w.
struct GemmDual {
    const float* in[2];
    const u16* wa[2];
    const float* rs[2]; const float* rb[2];
    u16* outLo[2]; u16* outHi[2];
};
template<int MT>
__global__ __launch_bounds__(256) void gemmln_kernel(GemmDual G){
    constexpr int KD = 64;
    constexpr int NW = MT*16*KD;
    __shared__ u16 wl[NW];
    int seg = blockIdx.x >> 10, tile = blockIdx.x & 1023;   // 1024 tiles/seg, 256 px each
    int w = threadIdx.x >> 6, lane = threadIdx.x & 63;
    int quad = lane >> 4, l16 = lane & 15;
    int b = tile >> 8;                                      // 256 tiles per batch
    int pbase = ((tile & 255) << 8) + (w << 6) + (l16 << 2);  // 4 consecutive px/lane

    const float* in = G.in[seg];
    // ks0 loads in flight during weight staging (16 B/lane, 256 B/quad-stream)
    f4 fin[8];
    #pragma unroll
    for (int j = 0; j < 8; j++)
        fin[j] = *(const f4*)(in + ((size_t)b*64 + quad*8 + j)*HW + pbase);

    {
        const u16* W = G.wa[seg];
        for (int i = threadIdx.x; i < NW/8; i += 256){
            int row = i >> 3, ch = i & 7;
            uint4 v = *(const uint4*)(W + row*KD + ch*8);
            *(uint4*)(wl + row*KD + ((ch ^ (row & 7)) << 3)) = v;
        }
    }
    __syncthreads();

    // ks1 loads issued immediately (hidden under ks0 convert+MFMA)
    f4 fin2[8];
    #pragma unroll
    for (int j = 0; j < 8; j++)
        fin2[j] = *(const f4*)(in + ((size_t)b*64 + 32 + quad*8 + j)*HW + pbase);

    float s1[4] = {0.f,0.f,0.f,0.f}, s2[4] = {0.f,0.f,0.f,0.f};
    f4 acc[MT][4];
    #pragma unroll
    for (int mi = 0; mi < MT; mi++)
        #pragma unroll
        for (int p = 0; p < 4; p++) acc[mi][p] = (f4){0.f,0.f,0.f,0.f};

    #pragma unroll
    for (int ks = 0; ks < 2; ks++){
        bh8 bfr[4];
        #pragma unroll
        for (int j = 0; j < 8; j++){
            f4 fv = (ks == 0) ? fin[j] : fin2[j];
            #pragma unroll
            for (int p = 0; p < 4; p++){
                float v = fv[p];
                s1[p] += v; s2[p] = fmaf(v, v, s2[p]);
                bfr[p][j] = (short)f2b(v);
            }
        }
        #pragma unroll
        for (int mi = 0; mi < MT; mi++){
            bh8 a;
            __builtin_memcpy(&a, wl + (mi*16 + l16)*KD + ((((ks<<2)+quad) ^ (l16 & 7)) << 3), 16);
            #pragma unroll
            for (int p = 0; p < 4; p++)
                acc[mi][p] = mfma16(a, bfr[p], acc[mi][p]);
        }
    }

    float mu[4], iv[4];
    #pragma unroll
    for (int p = 0; p < 4; p++){
        s1[p] += __shfl_xor(s1[p], 16); s1[p] += __shfl_xor(s1[p], 32);
        s2[p] += __shfl_xor(s2[p], 16); s2[p] += __shfl_xor(s2[p], 32);
        mu[p] = s1[p]*(1.f/64.f);
        iv[p] = rsqrtf(s2[p]*(1.f/64.f) - mu[p]*mu[p] + 1e-5f);
    }

    const float* rs = G.rs[seg]; const float* rb = G.rb[seg];
    u16* oLo = G.outLo[seg]; u16* oHi = G.outHi[seg];
    #pragma unroll
    for (int mi = 0; mi < MT; mi++)
    #pragma unroll
    for (int r = 0; r < 4; r++){
        int o = mi*16 + quad*4 + r;
        size_t pidx = ((size_t)b*64 + (o & 63))*HW + pbase;
        float rsv = rs[o], rbv = rb[o];
        float v0 = iv[0]*(acc[mi][0][r] - mu[0]*rsv) + rbv;
        float v1 = iv[1]*(acc[mi][1][r] - mu[1]*rsv) + rbv;
        float v2 = iv[2]*(acc[mi][2][r] - mu[2]*rsv) + rbv;
        float v3 = iv[3]*(acc[mi][3][r] - mu[3]*rsv) + rbv;
        uint2 st;
        st.x = (u32)f2b(v0) | ((u32)f2b(v1) << 16);
        st.y = (u32)f2b(v2) | ((u32)f2b(v3) << 16);
        u16* dst = (o < 64) ? oLo : oHi;
        *(uint2*)(dst + pidx) = st;
    }
}

// ---------------- depthwise 3x3, 6 planes in ONE dispatch, 8 px/thread ----------------
struct Dw6 { const u16* in[6]; u16* out[6]; const float* w[6]; int choff[6]; };
__global__ __launch_bounds__(256) void dw6_kernel(Dw6 A){
    int seg = blockIdx.x >> 13;                  // 6 segs x 8192 blocks
    int lid = ((blockIdx.x & 8191) << 8) + threadIdx.x;
    const u16* inp = A.in[seg];
    u16* outp      = A.out[seg];
    const float* wd = A.w[seg];
    int choff      = A.choff[seg];
    int bc = lid >> 13;
    int n8 = lid & 8191;
    int h = n8 >> 5, c8 = (n8 & 31) << 3;
    const float* wc = wd + ((size_t)((bc & 63) + choff))*9;
    const u16* p = inp + (size_t)bc*HW;
    float row[3][10];
    #pragma unroll
    for (int r = 0; r < 3; r++){
        int hh = h - 1 + r;
        bool ok = (unsigned)hh < 256u;
        const u16* pr = p + hh*256 + c8;
        if (ok){
            uint4 m = *(const uint4*)pr;
            row[r][1] = b2f((u16)m.x); row[r][2] = b2f((u16)(m.x>>16));
            row[r][3] = b2f((u16)m.y); row[r][4] = b2f((u16)(m.y>>16));
            row[r][5] = b2f((u16)m.z); row[r][6] = b2f((u16)(m.z>>16));
            row[r][7] = b2f((u16)m.w); row[r][8] = b2f((u16)(m.w>>16));
            row[r][0] = (c8 > 0)   ? b2f(pr[-1]) : 0.f;
            row[r][9] = (c8 < 248) ? b2f(pr[8])  : 0.f;
        } else {
            #pragma unroll
            for (int j = 0; j < 10; j++) row[r][j] = 0.f;
        }
    }
    float o[8];
    #pragma unroll
    for (int i = 0; i < 8; i++){
        float a = 0.f;
        #pragma unroll
        for (int r = 0; r < 3; r++){
            a = fmaf(wc[r*3+0], row[r][i],   a);
            a = fmaf(wc[r*3+1], row[r][i+1], a);
            a = fmaf(wc[r*3+2], row[r][i+2], a);
        }
        o[i] = a;
    }
    uint4 st;
    st.x = (u32)f2b(o[0]) | ((u32)f2b(o[1])<<16);
    st.y = (u32)f2b(o[2]) | ((u32)f2b(o[3])<<16);
    st.z = (u32)f2b(o[4]) | ((u32)f2b(o[5])<<16);
    st.w = (u32)f2b(o[6]) | ((u32)f2b(o[7])<<16);
    *(uint4*)(outp + (size_t)bc*HW + h*256 + c8) = st;
}

// ---------------- attention partial sums (Gram + norms), dual-branch ----------------
#define NSL 64
struct AttnDual { const u16* q[2]; const u16* k[2]; float* sums; };
__global__ __launch_bounds__(256) void attn_part_kernel(AttnDual AD){
    int seg = blockIdx.x >> 11;
    int blk = blockIdx.x & 2047;     // B*8*NSL
    int sl = blk & (NSL-1);
    int bh = blk >> 6;               // b*8+h
    int b = bh >> 3, h = bh & 7;
    const u16* qp = AD.q[seg] + ((size_t)b*64 + h*8)*HW + sl*(HW/NSL);
    const u16* kp = AD.k[seg] + ((size_t)b*64 + h*8)*HW + sl*(HW/NSL);
    float acc[80];
    #pragma unroll
    for (int i = 0; i < 80; i++) acc[i] = 0.f;
    int n0 = threadIdx.x << 2;
    float qv[8][4], kw[8][4];
    #pragma unroll
    for (int i = 0; i < 8; i++){
        uint2 mq = *(const uint2*)(qp + (size_t)i*HW + n0);
        uint2 mk = *(const uint2*)(kp + (size_t)i*HW + n0);
        qv[i][0] = b2f((u16)(mq.x & 0xffffu)); qv[i][1] = b2f((u16)(mq.x >> 16));
        qv[i][2] = b2f((u16)(mq.y & 0xffffu)); qv[i][3] = b2f((u16)(mq.y >> 16));
        kw[i][0] = b2f((u16)(mk.x & 0xffffu)); kw[i][1] = b2f((u16)(mk.x >> 16));
        kw[i][2] = b2f((u16)(mk.y & 0xffffu)); kw[i][3] = b2f((u16)(mk.y >> 16));
    }
    #pragma unroll
    for (int i = 0; i < 8; i++){
        #pragma unroll
        for (int u = 0; u < 4; u++){
            acc[64+i] = fmaf(qv[i][u], qv[i][u], acc[64+i]);
            acc[72+i] = fmaf(kw[i][u], kw[i][u], acc[72+i]);
        }
        #pragma unroll
        for (int j = 0; j < 8; j++)
            #pragma unroll
            for (int u = 0; u < 4; u++)
                acc[i*8+j] = fmaf(qv[i][u], kw[j][u], acc[i*8+j]);
    }
    __shared__ float sred[4][80];
    int lane = threadIdx.x & 63, wv = threadIdx.x >> 6;
    #pragma unroll
    for (int t = 0; t < 80; t++){
        float r = acc[t];
        r += __shfl_down(r, 32); r += __shfl_down(r, 16); r += __shfl_down(r, 8);
        r += __shfl_down(r, 4);  r += __shfl_down(r, 2);  r += __shfl_down(r, 1);
        if (lane == 0) sred[wv][t] = r;
    }
    __syncthreads();
    if (threadIdx.x < 80){
        int t = threadIdx.x;
        atomicAdd(&AD.sums[seg*2560 + bh*80 + t], sred[0][t]+sred[1][t]+sred[2][t]+sred[3][t]);
    }
}

// ---------------- softmax + Weff = po . attn, dual-branch ----------------
struct WeffDual { const float* sums; const float* temp; const float* po[2]; u16* weff[2]; };
__global__ __launch_bounds__(64) void weff_kernel(WeffDual WD){
    int seg = blockIdx.x >> 2;
    int b = blockIdx.x & 3;
    const float* po = WD.po[seg];
    u16* weff = WD.weff[seg];
    __shared__ float at[8][8][8];
    int t = threadIdx.x;
    {
        int h = t >> 3, i = t & 7;
        const float* f = WD.sums + seg*2560 + (b*8 + h)*80;
        float iq = 1.f / fmaxf(sqrtf(f[64+i]), 1e-12f);
        float tv = WD.temp[h];
        float row[8]; float m = -1e30f;
        #pragma unroll
        for (int j = 0; j < 8; j++){
            float ik = 1.f / fmaxf(sqrtf(f[72+j]), 1e-12f);
            row[j] = f[i*8+j]*iq*ik*tv;
            m = fmaxf(m, row[j]);
        }
        float s = 0.f;
        #pragma unroll
        for (int j = 0; j < 8; j++){ row[j] = expf(row[j]-m); s += row[j]; }
        float rsv = 1.f/s;
        #pragma unroll
        for (int j = 0; j < 8; j++) at[h][i][j] = row[j]*rsv;
    }
    __syncthreads();
    int o = t;
    for (int g = 0; g < 64; g++){
        int h = g >> 3, j = g & 7;
        float wv = 0.f;
        #pragma unroll
        for (int i = 0; i < 8; i++) wv = fmaf(po[o*64 + h*8 + i], at[h][i][j], wv);
        weff[b*4096 + o*64 + g] = f2b(wv);
    }
}

// ---------------- fused modulation + final GEMM, dual-branch, 4 px/lane ----------------
// All f32 streams (in, resid, out) at 16 B/lane; v at 8 B/lane.
// LDS [128 ch][128 u32] = 64 KB; uint2 (b64) DS ops, rot-swizzle ((ch>>2)&3)*8.
struct ModFinal {
    const float* in[2]; const u16* wa[2]; const u16* wb[2];
    const float* b0[2]; const float* b2[2]; const float* b1[2]; const float* b3[2];
    const u16* wf[2];
    const u16* v[2];
    const float* resid[2];
    float* out[2];
};
__global__ __launch_bounds__(256) void modfinal_kernel(ModFinal M){
    __shared__ u32 lds[128*128];
    int seg = blockIdx.x >> 10, tile = blockIdx.x & 1023;
    int w = threadIdx.x >> 6, lane = threadIdx.x & 63;
    int quad = lane >> 4, l16 = lane & 15;
    int b = tile >> 8;
    int pbase = ((tile & 255) << 8) + (w << 6) + (l16 << 2);  // 4 px/lane
    int pp = ((w << 4) + l16) << 1;                           // u32-pair base in 128-wide row

    const float* in = M.in[seg];
    const u16* wa = M.wa[seg];

    // ---- stage 1: all 16 channel loads in flight ----
    f4 fin[8], fin2[8];
    #pragma unroll
    for (int j = 0; j < 8; j++)
        fin[j] = *(const f4*)(in + ((size_t)b*64 + quad*8 + j)*HW + pbase);
    #pragma unroll
    for (int j = 0; j < 8; j++)
        fin2[j] = *(const f4*)(in + ((size_t)b*64 + 32 + quad*8 + j)*HW + pbase);

    f4 acc[8][4];
    #pragma unroll
    for (int mi = 0; mi < 8; mi++)
        #pragma unroll
        for (int p = 0; p < 4; p++) acc[mi][p] = (f4){0.f,0.f,0.f,0.f};

    #pragma unroll
    for (int ks = 0; ks < 2; ks++){
        bh8 bfr[4];
        #pragma unroll
        for (int j = 0; j < 8; j++){
            f4 fv = (ks == 0) ? fin[j] : fin2[j];
            #pragma unroll
            for (int p = 0; p < 4; p++) bfr[p][j] = (short)f2b(fv[p]);
        }
        #pragma unroll
        for (int mi = 0; mi < 8; mi++){
            bh8 a;
            __builtin_memcpy(&a, wa + (mi*16 + l16)*64 + ks*32 + quad*8, 16);
            #pragma unroll
            for (int p = 0; p < 4; p++)
                acc[mi][p] = mfma16(a, bfr[p], acc[mi][p]);
        }
    }

    // ---- v prefetch (uint2 = 4 px bf16): hidden under epi + barrier + stage 2 ----
    uint2 vpref[16];
    {
        const u16* vP = M.v[seg];
        #pragma unroll
        for (int mi = 0; mi < 4; mi++)
        #pragma unroll
        for (int r = 0; r < 4; r++)
            vpref[mi*4+r] = *(const uint2*)(vP + ((size_t)b*64 + mi*16 + quad*4 + r)*HW + pbase);
    }

    // ---- stage-1 epilogue: bias + lrelu -> LDS ----
    {
        const float* b0v = M.b0[seg]; const float* b2v = M.b2[seg];
        #pragma unroll
        for (int mi = 0; mi < 8; mi++)
        #pragma unroll
        for (int r = 0; r < 4; r++){
            int o = mi*16 + quad*4 + r;
            float bi = (o < 64) ? b0v[o] : b2v[o-64];
            float v0 = acc[mi][0][r] + bi; v0 = v0 > 0.f ? v0 : 0.1f*v0;
            float v1 = acc[mi][1][r] + bi; v1 = v1 > 0.f ? v1 : 0.1f*v1;
            float v2 = acc[mi][2][r] + bi; v2 = v2 > 0.f ? v2 : 0.1f*v2;
            float v3 = acc[mi][3][r] + bi; v3 = v3 > 0.f ? v3 : 0.1f*v3;
            uint2 st;
            st.x = (u32)f2b(v0) | ((u32)f2b(v1) << 16);
            st.y = (u32)f2b(v2) | ((u32)f2b(v3) << 16);
            *(uint2*)&lds[o*128 + ((pp + ((o>>2)&3)*8) & 127)] = st;
        }
    }
    __syncthreads();

    // ---- stage 2 (block-diag K=128) ----
    const u16* wb = M.wb[seg];
    f4 acc2[8][4];
    #pragma unroll
    for (int mi = 0; mi < 8; mi++)
        #pragma unroll
        for (int p = 0; p < 4; p++) acc2[mi][p] = (f4){0.f,0.f,0.f,0.f};
    #pragma unroll
    for (int ks = 0; ks < 4; ks++){
        int kb = ks*32 + quad*8;
        bh8 bfr[4];
        #pragma unroll
        for (int j = 0; j < 8; j++){
            int ch = kb + j;
            uint2 m = *(const uint2*)&lds[ch*128 + ((pp + ((ch>>2)&3)*8) & 127)];
            bfr[0][j] = (short)(m.x & 0xffffu);
            bfr[1][j] = (short)(m.x >> 16);
            bfr[2][j] = (short)(m.y & 0xffffu);
            bfr[3][j] = (short)(m.y >> 16);
        }
        #pragma unroll
        for (int mi = 0; mi < 8; mi++){
            if (mi < 4 ? (ks < 2) : (ks >= 2)){
                int ksl = (mi >= 4) ? ks - 2 : ks;
                bh8 a;
                __builtin_memcpy(&a, wb + (mi*16 + l16)*64 + ksl*32 + quad*8, 16);
                #pragma unroll
                for (int p = 0; p < 4; p++)
                    acc2[mi][p] = mfma16(a, bfr[p], acc2[mi][p]);
            }
        }
    }
    __syncthreads();   // stage-2 reads done before v' overwrite

    // ---- vmod: v' = v*(s+1)+t -> LDS rows 0..63 ----
    {
        const float* b1v = M.b1[seg]; const float* b3v = M.b3[seg];
        #pragma unroll
        for (int mi = 0; mi < 4; mi++)
        #pragma unroll
        for (int r = 0; r < 4; r++){
            int o = mi*16 + quad*4 + r;
            uint2 vv = vpref[mi*4+r];
            float va[4] = { b2f((u16)(vv.x & 0xffffu)), b2f((u16)(vv.x >> 16)),
                            b2f((u16)(vv.y & 0xffffu)), b2f((u16)(vv.y >> 16)) };
            float ov[4];
            #pragma unroll
            for (int p = 0; p < 4; p++){
                float s = acc2[mi][p][r] + b1v[o];
                float t = acc2[mi+4][p][r] + b3v[o];
                ov[p] = va[p]*(s+1.f)+t;
            }
            uint2 st;
            st.x = (u32)f2b(ov[0]) | ((u32)f2b(ov[1]) << 16);
            st.y = (u32)f2b(ov[2]) | ((u32)f2b(ov[3]) << 16);
            *(uint2*)&lds[o*128 + ((pp + ((o>>2)&3)*8) & 127)] = st;
        }
    }
    // ---- resid prefetch (float4): hidden across barrier + stage 3 ----
    f4 rpre[16];
    {
        const float* resid = M.resid[seg];
        #pragma unroll
        for (int mi = 0; mi < 4; mi++)
        #pragma unroll
        for (int r = 0; r < 4; r++)
            rpre[mi*4+r] = *(const f4*)(resid + ((size_t)b*64 + mi*16 + quad*4 + r)*HW + pbase);
    }
    __syncthreads();

    // ---- stage 3: out = Weff . v' + resid ----
    const u16* wf = M.wf[seg] + b*4096;
    f4 accF[4][4];
    #pragma unroll
    for (int mi = 0; mi < 4; mi++)
        #pragma unroll
        for (int p = 0; p < 4; p++) accF[mi][p] = (f4){0.f,0.f,0.f,0.f};
    #pragma unroll
    for (int ks = 0; ks < 2; ks++){
        int kb = ks*32 + quad*8;
        bh8 bfr[4];
        #pragma unroll
        for (int j = 0; j < 8; j++){
            int ch = kb + j;
            uint2 m = *(const uint2*)&lds[ch*128 + ((pp + ((ch>>2)&3)*8) & 127)];
            bfr[0][j] = (short)(m.x & 0xffffu);
            bfr[1][j] = (short)(m.x >> 16);
            bfr[2][j] = (short)(m.y & 0xffffu);
            bfr[3][j] = (short)(m.y >> 16);
        }
        #pragma unroll
        for (int mi = 0; mi < 4; mi++){
            bh8 a;
            __builtin_memcpy(&a, wf + (mi*16 + l16)*64 + ks*32 + quad*8, 16);
            #pragma unroll
            for (int p = 0; p < 4; p++)
                accF[mi][p] = mfma16(a, bfr[p], accF[mi][p]);
        }
    }
    {
        float* outF = M.out[seg];
        #pragma unroll
        for (int mi = 0; mi < 4; mi++)
        #pragma unroll
        for (int r = 0; r < 4; r++){
            int o = mi*16 + quad*4 + r;
            size_t pidx = ((size_t)b*64 + o)*HW + pbase;
            f4 rr = rpre[mi*4+r];
            f4 st;
            #pragma unroll
            for (int p = 0; p < 4; p++) st[p] = accF[mi][p][r] + rr[p];
            *(f4*)(outF + pidx) = st;
        }
    }
}

extern "C" void kernel_launch(void* const* d_in, const int* in_sizes, int n_in,
                              void* d_out, int out_size, void* d_ws, size_t ws_size,
                              hipStream_t stream){
    const float* x    = (const float*)d_in[0];
    const float* y    = (const float*)d_in[1];
    const float* ln_w = (const float*)d_in[2];
    const float* ln_b = (const float*)d_in[3];
    const float* temp = (const float*)d_in[4];
    const float* kv_w[2]   = {(const float*)d_in[5],  (const float*)d_in[10]};
    const float* kvdw_w[2] = {(const float*)d_in[6],  (const float*)d_in[11]};
    const float* q_w[2]    = {(const float*)d_in[7],  (const float*)d_in[12]};
    const float* qdw_w[2]  = {(const float*)d_in[8],  (const float*)d_in[13]};
    const float* po_w[2]   = {(const float*)d_in[9],  (const float*)d_in[14]};
    const float* mm_w[2]   = {(const float*)d_in[15], (const float*)d_in[17]};
    const float* mm_b[2]   = {(const float*)d_in[16], (const float*)d_in[18]};

    const size_t HPE = (size_t)BATCH*64*HW;   // elems per 64-ch plane
    u16* PL = (u16*)d_ws;                     // 12 planes
    u16* P[12];
    for (int i = 0; i < 12; i++) P[i] = PL + (size_t)i*HPE;
    float* sums = (float*)(PL + 12*HPE);      // 2 * 2560 f32
    float* lnc  = sums + 5120;                // 768 f32 LN rowsum constants
    u16* warena = (u16*)(lnc + 768);
    const int WKV[2] = {0, 8192}, WQ[2] = {16384, 20480};
    const int WMA[2] = {24576, 40960}, WMB[2] = {32768, 49152};
    const int WEFF[2] = {57344, 73728};

    size_t need = 12*HPE*2 + (5120+768)*4 + 90112*2;
    if (ws_size < need) return;

    SetupArgs S{};
    int nj = 0;
    auto add = [&](const float* s, u16* d, int n, const float* cs){ S.j[nj] = {s, d, n, cs}; nj++; };
    for (int br = 0; br < 2; br++){
        add(kv_w[br],        warena + WKV[br],        8192, ln_w);
        add(q_w[br],         warena + WQ[br],         4096, ln_w);
        add(mm_w[br],        warena + WMA[br],        4096, nullptr);  // W0 -> rows 0-63
        add(mm_w[br]+8192,   warena + WMA[br] + 4096, 4096, nullptr);  // W2 -> rows 64-127
        add(mm_w[br]+4096,   warena + WMB[br],        4096, nullptr);  // W1 -> rows 0-63
        add(mm_w[br]+12288,  warena + WMB[br] + 4096, 4096, nullptr);  // W3 -> rows 64-127
    }
    S.kvw[0] = kv_w[0]; S.kvw[1] = kv_w[1];
    S.qw[0]  = q_w[0];  S.qw[1]  = q_w[1];
    S.lnw = ln_w; S.lnb = ln_b; S.sums = sums; S.lnc = lnc;
    setup_kernel<<<17, 256, 0, stream>>>(S);

    const int GT = NPIX/256;     // 1024 gemm tiles per branch (256 px each)

    // kv conv both branches: br0 x -> P0(k),P1(v); br1 y -> P2(k),P3(v)
    GemmDual GK{};
    GK.in[0] = x; GK.in[1] = y;
    GK.wa[0] = warena + WKV[0]; GK.wa[1] = warena + WKV[1];
    GK.rs[0] = lnc;        GK.rb[0] = lnc + 128;
    GK.rs[1] = lnc + 256;  GK.rb[1] = lnc + 384;
    GK.outLo[0] = P[0]; GK.outHi[0] = P[1];
    GK.outLo[1] = P[2]; GK.outHi[1] = P[3];
    gemmln_kernel<8><<<2*GT, 256, 0, stream>>>(GK);

    // q conv both branches: br0 y -> P4; br1 x -> P5
    GemmDual GQ{};
    GQ.in[0] = y; GQ.in[1] = x;
    GQ.wa[0] = warena + WQ[0]; GQ.wa[1] = warena + WQ[1];
    GQ.rs[0] = lnc + 512;  GQ.rb[0] = lnc + 576;
    GQ.rs[1] = lnc + 640;  GQ.rb[1] = lnc + 704;
    GQ.outLo[0] = P[4]; GQ.outHi[0] = P[4];
    GQ.outLo[1] = P[5]; GQ.outHi[1] = P[5];
    gemmln_kernel<4><<<2*GT, 256, 0, stream>>>(GQ);

    // depthwise, all 6 planes in one dispatch:
    // br0: P0->P6 (k), P1->P7 (v), P4->P8 (q); br1: P2->P9, P3->P10, P5->P11
    Dw6 D{};
    D.in[0] = P[0];  D.out[0] = P[6];  D.w[0] = kvdw_w[0]; D.choff[0] = 0;
    D.in[1] = P[1];  D.out[1] = P[7];  D.w[1] = kvdw_w[0]; D.choff[1] = 64;
    D.in[2] = P[4];  D.out[2] = P[8];  D.w[2] = qdw_w[0];  D.choff[2] = 0;
    D.in[3] = P[2];  D.out[3] = P[9];  D.w[3] = kvdw_w[1]; D.choff[3] = 0;
    D.in[4] = P[3];  D.out[4] = P[10]; D.w[4] = kvdw_w[1]; D.choff[4] = 64;
    D.in[5] = P[5];  D.out[5] = P[11]; D.w[5] = qdw_w[1];  D.choff[5] = 0;
    dw6_kernel<<<6*8192, 256, 0, stream>>>(D);

    // attention stats both branches
    AttnDual AD{};
    AD.q[0] = P[8];  AD.k[0] = P[6];
    AD.q[1] = P[11]; AD.k[1] = P[9];
    AD.sums = sums;
    attn_part_kernel<<<2*BATCH*8*NSL, 256, 0, stream>>>(AD);

    // softmax + Weff both branches
    WeffDual WD{};
    WD.sums = sums; WD.temp = temp;
    WD.po[0] = po_w[0]; WD.po[1] = po_w[1];
    WD.weff[0] = warena + WEFF[0]; WD.weff[1] = warena + WEFF[1];
    weff_kernel<<<2*BATCH, 64, 0, stream>>>(WD);

    // fused modulation + final both branches
    float* outp = (float*)d_out;
    ModFinal M{};
    M.in[0] = x; M.in[1] = y;
    M.wa[0] = warena + WMA[0]; M.wa[1] = warena + WMA[1];
    M.wb[0] = warena + WMB[0]; M.wb[1] = warena + WMB[1];
    M.b0[0] = mm_b[0];       M.b0[1] = mm_b[1];
    M.b2[0] = mm_b[0] + 128; M.b2[1] = mm_b[1] + 128;
    M.b1[0] = mm_b[0] + 64;  M.b1[1] = mm_b[1] + 64;
    M.b3[0] = mm_b[0] + 192; M.b3[1] = mm_b[1] + 192;
    M.wf[0] = warena + WEFF[0]; M.wf[1] = warena + WEFF[1];
    M.v[0] = P[7]; M.v[1] = P[10];
    M.resid[0] = y; M.resid[1] = x;
    M.out[0] = outp; M.out[1] = outp + HPE;
    modfinal_kernel<<<2*GT, 256, 0, stream>>>(M);
}

// Round 7
// 611.660 us; speedup vs baseline: 1.4464x; 1.1359x over previous
//
#include <hip/hip_runtime.h>
#include <hip/hip_bf16.h>

#define HW 65536
#define BATCH 4
#define NPIX (BATCH*HW)   // 262144 pixels

typedef unsigned short u16;
typedef unsigned int   u32;
typedef __attribute__((ext_vector_type(8))) short bh8;   // 8 bf16 (A/B frag, 4 VGPRs)
typedef __attribute__((ext_vector_type(4))) float f4;    // 4 f32 (C/D frag)

__device__ __forceinline__ float b2f(u16 u){
    u32 i = ((u32)u) << 16; float f; __builtin_memcpy(&f, &i, 4); return f;
}
__device__ __forceinline__ u16 f2b(float f){
    __hip_bfloat16 h = __float2bfloat16(f); u16 u; __builtin_memcpy(&u, &h, 2); return u;
}

__device__ __forceinline__ f4 mfma16(bh8 a, bh8 b, f4 c){
    return __builtin_amdgcn_mfma_f32_16x16x32_bf16(a, b, c, 0, 0, 0);
}

// ---------------- setup: weight cvt + LN rowsums + zero sums, one dispatch ----------------
struct CvtJob { const float* src; u16* dst; int n; const float* cs; };
struct SetupArgs {
    CvtJob j[12];
    const float* kvw[2]; const float* qw[2];
    const float* lnw; const float* lnb;
    float* sums; float* lnc;
};
__global__ __launch_bounds__(256) void setup_kernel(SetupArgs S){
    int blk = blockIdx.x;
    if (blk < 12){
        const CvtJob J = S.j[blk];
        if (J.cs){
            for (int i = threadIdx.x; i < J.n; i += 256) J.dst[i] = f2b(J.src[i] * J.cs[i & 63]);
        } else {
            for (int i = threadIdx.x; i < J.n; i += 256) J.dst[i] = f2b(J.src[i]);
        }
        return;
    }
    int pb = blk - 12;
    if (pb == 0){
        for (int i = threadIdx.x; i < 5120; i += 256) S.sums[i] = 0.f;
    } else {
        // lnc rowsums for merged gemm: seg = pb-1; rows 0-127 kv_w[seg], 128-191 q_w[1-seg]
        int seg = pb - 1;
        int o = threadIdx.x;
        if (o < 192){
            const float* W = (o < 128) ? S.kvw[seg] : S.qw[1-seg];
            int row = (o < 128) ? o : o - 128;
            float a = 0.f, bb = 0.f;
            for (int c = 0; c < 64; c++){
                float wv = W[row*64 + c];
                a = fmaf(wv, S.lnw[c], a); bb = fmaf(wv, S.lnb[c], bb);
            }
            S.lnc[seg*384 + o] = a; S.lnc[seg*384 + 192 + o] = bb;
        }
    }
}

// ---------------- merged LN-folded 1x1 conv GEMM: M=192 (kv + other-branch q) ----------------
// seg0 reads x: rows 0-63 -> k-pre(br0), 64-127 -> v-pre(br0), 128-191 -> q-pre(br1)
// seg1 reads y: analogous for br1/br0.
// Per-mi acc (16 VGPR live) keeps register pressure low despite M=192.
struct GemmMerged {
    const float* in[2];
    const u16* wa[2];               // 192x64 bf16, pre-scaled by ln_w
    const float* rs[2]; const float* rb[2];   // 192 each
    u16* out0[2]; u16* out1[2]; u16* out2[2]; // kvLo, kvHi, q
};
__global__ __launch_bounds__(256) void gemmln_kernel(GemmMerged G){
    __shared__ u16 wl[192*64];
    int seg = blockIdx.x >> 10, tile = blockIdx.x & 1023;   // 1024 tiles/seg, 256 px each
    int w = threadIdx.x >> 6, lane = threadIdx.x & 63;
    int quad = lane >> 4, l16 = lane & 15;
    int b = tile >> 8;
    int pbase = ((tile & 255) << 8) + (w << 6) + (l16 << 2);  // 4 consecutive px/lane

    const float* in = G.in[seg];
    // all 16 channel-group loads in flight across weight staging + barrier
    f4 fin[8], fin2[8];
    #pragma unroll
    for (int j = 0; j < 8; j++)
        fin[j] = *(const f4*)(in + ((size_t)b*64 + quad*8 + j)*HW + pbase);
    #pragma unroll
    for (int j = 0; j < 8; j++)
        fin2[j] = *(const f4*)(in + ((size_t)b*64 + 32 + quad*8 + j)*HW + pbase);

    {
        const u16* W = G.wa[seg];
        for (int i = threadIdx.x; i < 192*8; i += 256){
            int row = i >> 3, ch = i & 7;
            uint4 v = *(const uint4*)(W + row*64 + ch*8);
            *(uint4*)(wl + row*64 + ((ch ^ (row & 7)) << 3)) = v;
        }
    }
    __syncthreads();

    // stats + bf16 fragments for both k-steps
    float s1[4] = {0.f,0.f,0.f,0.f}, s2[4] = {0.f,0.f,0.f,0.f};
    bh8 bfr[2][4];
    #pragma unroll
    for (int j = 0; j < 8; j++){
        f4 fv = fin[j];
        #pragma unroll
        for (int p = 0; p < 4; p++){
            float v = fv[p];
            s1[p] += v; s2[p] = fmaf(v, v, s2[p]);
            bfr[0][p][j] = (short)f2b(v);
        }
    }
    #pragma unroll
    for (int j = 0; j < 8; j++){
        f4 fv = fin2[j];
        #pragma unroll
        for (int p = 0; p < 4; p++){
            float v = fv[p];
            s1[p] += v; s2[p] = fmaf(v, v, s2[p]);
            bfr[1][p][j] = (short)f2b(v);
        }
    }

    float mu[4], iv[4];
    #pragma unroll
    for (int p = 0; p < 4; p++){
        s1[p] += __shfl_xor(s1[p], 16); s1[p] += __shfl_xor(s1[p], 32);
        s2[p] += __shfl_xor(s2[p], 16); s2[p] += __shfl_xor(s2[p], 32);
        mu[p] = s1[p]*(1.f/64.f);
        iv[p] = rsqrtf(s2[p]*(1.f/64.f) - mu[p]*mu[p] + 1e-5f);
    }

    const float* rs = G.rs[seg]; const float* rb = G.rb[seg];
    u16* o0 = G.out0[seg]; u16* o1 = G.out1[seg]; u16* o2 = G.out2[seg];
    #pragma unroll
    for (int mi = 0; mi < 12; mi++){
        f4 acc[4];
        #pragma unroll
        for (int p = 0; p < 4; p++) acc[p] = (f4){0.f,0.f,0.f,0.f};
        #pragma unroll
        for (int ks = 0; ks < 2; ks++){
            bh8 a;
            __builtin_memcpy(&a, wl + (mi*16 + l16)*64 + ((((ks<<2)+quad) ^ (l16 & 7)) << 3), 16);
            #pragma unroll
            for (int p = 0; p < 4; p++)
                acc[p] = mfma16(a, bfr[ks][p], acc[p]);
        }
        u16* dst = (mi < 4) ? o0 : (mi < 8) ? o1 : o2;
        #pragma unroll
        for (int r = 0; r < 4; r++){
            int o = mi*16 + quad*4 + r;
            size_t pidx = ((size_t)b*64 + (o & 63))*HW + pbase;
            float rsv = rs[o], rbv = rb[o];
            float v0 = iv[0]*(acc[0][r] - mu[0]*rsv) + rbv;
            float v1 = iv[1]*(acc[1][r] - mu[1]*rsv) + rbv;
            float v2 = iv[2]*(acc[2][r] - mu[2]*rsv) + rbv;
            float v3 = iv[3]*(acc[3][r] - mu[3]*rsv) + rbv;
            uint2 st;
            st.x = (u32)f2b(v0) | ((u32)f2b(v1) << 16);
            st.y = (u32)f2b(v2) | ((u32)f2b(v3) << 16);
            *(uint2*)(dst + pidx) = st;
        }
    }
}

// ---------------- depthwise 3x3, 6 planes in ONE dispatch, 8 px/thread ----------------
// Halo pixels via cross-lane shuffle (no fine-grained 2B loads):
// lane i's left halo = lane i-1's element 8; right halo = lane i+1's element 1.
// Image-edge lanes (c8==0 / c8==248) are exactly wave positions 0/31 per row group.
struct Dw6 { const u16* in[6]; u16* out[6]; const float* w[6]; int choff[6]; };
__global__ __launch_bounds__(256) void dw6_kernel(Dw6 A){
    int seg = blockIdx.x >> 13;                  // 6 segs x 8192 blocks
    int lid = ((blockIdx.x & 8191) << 8) + threadIdx.x;
    const u16* inp = A.in[seg];
    u16* outp      = A.out[seg];
    const float* wd = A.w[seg];
    int choff      = A.choff[seg];
    int bc = lid >> 13;
    int n8 = lid & 8191;
    int h = n8 >> 5, c8 = (n8 & 31) << 3;
    const float* wc = wd + ((size_t)((bc & 63) + choff))*9;
    const u16* p = inp + (size_t)bc*HW;
    float row[3][10];
    #pragma unroll
    for (int r = 0; r < 3; r++){
        int hh = h - 1 + r;
        bool ok = (unsigned)hh < 256u;
        const u16* pr = p + hh*256 + c8;
        if (ok){
            uint4 m = *(const uint4*)pr;
            row[r][1] = b2f((u16)m.x); row[r][2] = b2f((u16)(m.x>>16));
            row[r][3] = b2f((u16)m.y); row[r][4] = b2f((u16)(m.y>>16));
            row[r][5] = b2f((u16)m.z); row[r][6] = b2f((u16)(m.z>>16));
            row[r][7] = b2f((u16)m.w); row[r][8] = b2f((u16)(m.w>>16));
        } else {
            #pragma unroll
            for (int j = 1; j < 9; j++) row[r][j] = 0.f;
        }
        float lft = __shfl_up(row[r][8], 1);
        float rgt = __shfl_down(row[r][1], 1);
        row[r][0] = (c8 > 0)   ? lft : 0.f;
        row[r][9] = (c8 < 248) ? rgt : 0.f;
    }
    float o[8];
    #pragma unroll
    for (int i = 0; i < 8; i++){
        float a = 0.f;
        #pragma unroll
        for (int r = 0; r < 3; r++){
            a = fmaf(wc[r*3+0], row[r][i],   a);
            a = fmaf(wc[r*3+1], row[r][i+1], a);
            a = fmaf(wc[r*3+2], row[r][i+2], a);
        }
        o[i] = a;
    }
    uint4 st;
    st.x = (u32)f2b(o[0]) | ((u32)f2b(o[1])<<16);
    st.y = (u32)f2b(o[2]) | ((u32)f2b(o[3])<<16);
    st.z = (u32)f2b(o[4]) | ((u32)f2b(o[5])<<16);
    st.w = (u32)f2b(o[6]) | ((u32)f2b(o[7])<<16);
    *(uint4*)(outp + (size_t)bc*HW + h*256 + c8) = st;
}

// ---------------- attention partial sums (Gram + norms), dual-branch ----------------
#define NSL 64
struct AttnDual { const u16* q[2]; const u16* k[2]; float* sums; };
__global__ __launch_bounds__(256) void attn_part_kernel(AttnDual AD){
    int seg = blockIdx.x >> 11;
    int blk = blockIdx.x & 2047;     // B*8*NSL
    int sl = blk & (NSL-1);
    int bh = blk >> 6;               // b*8+h
    int b = bh >> 3, h = bh & 7;
    const u16* qp = AD.q[seg] + ((size_t)b*64 + h*8)*HW + sl*(HW/NSL);
    const u16* kp = AD.k[seg] + ((size_t)b*64 + h*8)*HW + sl*(HW/NSL);
    float acc[80];
    #pragma unroll
    for (int i = 0; i < 80; i++) acc[i] = 0.f;
    int n0 = threadIdx.x << 2;
    float qv[8][4], kw[8][4];
    #pragma unroll
    for (int i = 0; i < 8; i++){
        uint2 mq = *(const uint2*)(qp + (size_t)i*HW + n0);
        uint2 mk = *(const uint2*)(kp + (size_t)i*HW + n0);
        qv[i][0] = b2f((u16)(mq.x & 0xffffu)); qv[i][1] = b2f((u16)(mq.x >> 16));
        qv[i][2] = b2f((u16)(mq.y & 0xffffu)); qv[i][3] = b2f((u16)(mq.y >> 16));
        kw[i][0] = b2f((u16)(mk.x & 0xffffu)); kw[i][1] = b2f((u16)(mk.x >> 16));
        kw[i][2] = b2f((u16)(mk.y & 0xffffu)); kw[i][3] = b2f((u16)(mk.y >> 16));
    }
    #pragma unroll
    for (int i = 0; i < 8; i++){
        #pragma unroll
        for (int u = 0; u < 4; u++){
            acc[64+i] = fmaf(qv[i][u], qv[i][u], acc[64+i]);
            acc[72+i] = fmaf(kw[i][u], kw[i][u], acc[72+i]);
        }
        #pragma unroll
        for (int j = 0; j < 8; j++)
            #pragma unroll
            for (int u = 0; u < 4; u++)
                acc[i*8+j] = fmaf(qv[i][u], kw[j][u], acc[i*8+j]);
    }
    __shared__ float sred[4][80];
    int lane = threadIdx.x & 63, wv = threadIdx.x >> 6;
    #pragma unroll
    for (int t = 0; t < 80; t++){
        float r = acc[t];
        r += __shfl_down(r, 32); r += __shfl_down(r, 16); r += __shfl_down(r, 8);
        r += __shfl_down(r, 4);  r += __shfl_down(r, 2);  r += __shfl_down(r, 1);
        if (lane == 0) sred[wv][t] = r;
    }
    __syncthreads();
    if (threadIdx.x < 80){
        int t = threadIdx.x;
        atomicAdd(&AD.sums[seg*2560 + bh*80 + t], sred[0][t]+sred[1][t]+sred[2][t]+sred[3][t]);
    }
}

// ---------------- softmax + Weff = po . attn, dual-branch ----------------
struct WeffDual { const float* sums; const float* temp; const float* po[2]; u16* weff[2]; };
__global__ __launch_bounds__(64) void weff_kernel(WeffDual WD){
    int seg = blockIdx.x >> 2;
    int b = blockIdx.x & 3;
    const float* po = WD.po[seg];
    u16* weff = WD.weff[seg];
    __shared__ float at[8][8][8];
    int t = threadIdx.x;
    {
        int h = t >> 3, i = t & 7;
        const float* f = WD.sums + seg*2560 + (b*8 + h)*80;
        float iq = 1.f / fmaxf(sqrtf(f[64+i]), 1e-12f);
        float tv = WD.temp[h];
        float row[8]; float m = -1e30f;
        #pragma unroll
        for (int j = 0; j < 8; j++){
            float ik = 1.f / fmaxf(sqrtf(f[72+j]), 1e-12f);
            row[j] = f[i*8+j]*iq*ik*tv;
            m = fmaxf(m, row[j]);
        }
        float s = 0.f;
        #pragma unroll
        for (int j = 0; j < 8; j++){ row[j] = expf(row[j]-m); s += row[j]; }
        float rsv = 1.f/s;
        #pragma unroll
        for (int j = 0; j < 8; j++) at[h][i][j] = row[j]*rsv;
    }
    __syncthreads();
    int o = t;
    for (int g = 0; g < 64; g++){
        int h = g >> 3, j = g & 7;
        float wv = 0.f;
        #pragma unroll
        for (int i = 0; i < 8; i++) wv = fmaf(po[o*64 + h*8 + i], at[h][i][j], wv);
        weff[b*4096 + o*64 + g] = f2b(wv);
    }
}

// ---------------- fused modulation + final GEMM, dual-branch, 4 px/lane ----------------
struct ModFinal {
    const float* in[2]; const u16* wa[2]; const u16* wb[2];
    const float* b0[2]; const float* b2[2]; const float* b1[2]; const float* b3[2];
    const u16* wf[2];
    const u16* v[2];
    const float* resid[2];
    float* out[2];
};
__global__ __launch_bounds__(256) void modfinal_kernel(ModFinal M){
    __shared__ u32 lds[128*128];
    int seg = blockIdx.x >> 10, tile = blockIdx.x & 1023;
    int w = threadIdx.x >> 6, lane = threadIdx.x & 63;
    int quad = lane >> 4, l16 = lane & 15;
    int b = tile >> 8;
    int pbase = ((tile & 255) << 8) + (w << 6) + (l16 << 2);  // 4 px/lane
    int pp = ((w << 4) + l16) << 1;                           // u32-pair base in 128-wide row

    const float* in = M.in[seg];
    const u16* wa = M.wa[seg];

    // ---- stage 1: all 16 channel loads in flight ----
    f4 fin[8], fin2[8];
    #pragma unroll
    for (int j = 0; j < 8; j++)
        fin[j] = *(const f4*)(in + ((size_t)b*64 + quad*8 + j)*HW + pbase);
    #pragma unroll
    for (int j = 0; j < 8; j++)
        fin2[j] = *(const f4*)(in + ((size_t)b*64 + 32 + quad*8 + j)*HW + pbase);

    f4 acc[8][4];
    #pragma unroll
    for (int mi = 0; mi < 8; mi++)
        #pragma unroll
        for (int p = 0; p < 4; p++) acc[mi][p] = (f4){0.f,0.f,0.f,0.f};

    #pragma unroll
    for (int ks = 0; ks < 2; ks++){
        bh8 bfr[4];
        #pragma unroll
        for (int j = 0; j < 8; j++){
            f4 fv = (ks == 0) ? fin[j] : fin2[j];
            #pragma unroll
            for (int p = 0; p < 4; p++) bfr[p][j] = (short)f2b(fv[p]);
        }
        #pragma unroll
        for (int mi = 0; mi < 8; mi++){
            bh8 a;
            __builtin_memcpy(&a, wa + (mi*16 + l16)*64 + ks*32 + quad*8, 16);
            #pragma unroll
            for (int p = 0; p < 4; p++)
                acc[mi][p] = mfma16(a, bfr[p], acc[mi][p]);
        }
    }

    // ---- v prefetch (uint2 = 4 px bf16): hidden under epi + barrier + stage 2 ----
    uint2 vpref[16];
    {
        const u16* vP = M.v[seg];
        #pragma unroll
        for (int mi = 0; mi < 4; mi++)
        #pragma unroll
        for (int r = 0; r < 4; r++)
            vpref[mi*4+r] = *(const uint2*)(vP + ((size_t)b*64 + mi*16 + quad*4 + r)*HW + pbase);
    }

    // ---- stage-1 epilogue: bias + lrelu -> LDS ----
    {
        const float* b0v = M.b0[seg]; const float* b2v = M.b2[seg];
        #pragma unroll
        for (int mi = 0; mi < 8; mi++)
        #pragma unroll
        for (int r = 0; r < 4; r++){
            int o = mi*16 + quad*4 + r;
            float bi = (o < 64) ? b0v[o] : b2v[o-64];
            float v0 = acc[mi][0][r] + bi; v0 = v0 > 0.f ? v0 : 0.1f*v0;
            float v1 = acc[mi][1][r] + bi; v1 = v1 > 0.f ? v1 : 0.1f*v1;
            float v2 = acc[mi][2][r] + bi; v2 = v2 > 0.f ? v2 : 0.1f*v2;
            float v3 = acc[mi][3][r] + bi; v3 = v3 > 0.f ? v3 : 0.1f*v3;
            uint2 st;
            st.x = (u32)f2b(v0) | ((u32)f2b(v1) << 16);
            st.y = (u32)f2b(v2) | ((u32)f2b(v3) << 16);
            *(uint2*)&lds[o*128 + ((pp + ((o>>2)&3)*8) & 127)] = st;
        }
    }
    __syncthreads();

    // ---- stage 2 (block-diag K=128) ----
    const u16* wb = M.wb[seg];
    f4 acc2[8][4];
    #pragma unroll
    for (int mi = 0; mi < 8; mi++)
        #pragma unroll
        for (int p = 0; p < 4; p++) acc2[mi][p] = (f4){0.f,0.f,0.f,0.f};
    #pragma unroll
    for (int ks = 0; ks < 4; ks++){
        int kb = ks*32 + quad*8;
        bh8 bfr[4];
        #pragma unroll
        for (int j = 0; j < 8; j++){
            int ch = kb + j;
            uint2 m = *(const uint2*)&lds[ch*128 + ((pp + ((ch>>2)&3)*8) & 127)];
            bfr[0][j] = (short)(m.x & 0xffffu);
            bfr[1][j] = (short)(m.x >> 16);
            bfr[2][j] = (short)(m.y & 0xffffu);
            bfr[3][j] = (short)(m.y >> 16);
        }
        #pragma unroll
        for (int mi = 0; mi < 8; mi++){
            if (mi < 4 ? (ks < 2) : (ks >= 2)){
                int ksl = (mi >= 4) ? ks - 2 : ks;
                bh8 a;
                __builtin_memcpy(&a, wb + (mi*16 + l16)*64 + ksl*32 + quad*8, 16);
                #pragma unroll
                for (int p = 0; p < 4; p++)
                    acc2[mi][p] = mfma16(a, bfr[p], acc2[mi][p]);
            }
        }
    }
    __syncthreads();   // stage-2 reads done before v' overwrite

    // ---- vmod: v' = v*(s+1)+t -> LDS rows 0..63 ----
    {
        const float* b1v = M.b1[seg]; const float* b3v = M.b3[seg];
        #pragma unroll
        for (int mi = 0; mi < 4; mi++)
        #pragma unroll
        for (int r = 0; r < 4; r++){
            int o = mi*16 + quad*4 + r;
            uint2 vv = vpref[mi*4+r];
            float va[4] = { b2f((u16)(vv.x & 0xffffu)), b2f((u16)(vv.x >> 16)),
                            b2f((u16)(vv.y & 0xffffu)), b2f((u16)(vv.y >> 16)) };
            float ov[4];
            #pragma unroll
            for (int p = 0; p < 4; p++){
                float s = acc2[mi][p][r] + b1v[o];
                float t = acc2[mi+4][p][r] + b3v[o];
                ov[p] = va[p]*(s+1.f)+t;
            }
            uint2 st;
            st.x = (u32)f2b(ov[0]) | ((u32)f2b(ov[1]) << 16);
            st.y = (u32)f2b(ov[2]) | ((u32)f2b(ov[3]) << 16);
            *(uint2*)&lds[o*128 + ((pp + ((o>>2)&3)*8) & 127)] = st;
        }
    }
    // ---- resid prefetch (float4): hidden across barrier + stage 3 ----
    f4 rpre[16];
    {
        const float* resid = M.resid[seg];
        #pragma unroll
        for (int mi = 0; mi < 4; mi++)
        #pragma unroll
        for (int r = 0; r < 4; r++)
            rpre[mi*4+r] = *(const f4*)(resid + ((size_t)b*64 + mi*16 + quad*4 + r)*HW + pbase);
    }
    __syncthreads();

    // ---- stage 3: out = Weff . v' + resid ----
    const u16* wf = M.wf[seg] + b*4096;
    f4 accF[4][4];
    #pragma unroll
    for (int mi = 0; mi < 4; mi++)
        #pragma unroll
        for (int p = 0; p < 4; p++) accF[mi][p] = (f4){0.f,0.f,0.f,0.f};
    #pragma unroll
    for (int ks = 0; ks < 2; ks++){
        int kb = ks*32 + quad*8;
        bh8 bfr[4];
        #pragma unroll
        for (int j = 0; j < 8; j++){
            int ch = kb + j;
            uint2 m = *(const uint2*)&lds[ch*128 + ((pp + ((ch>>2)&3)*8) & 127)];
            bfr[0][j] = (short)(m.x & 0xffffu);
            bfr[1][j] = (short)(m.x >> 16);
            bfr[2][j] = (short)(m.y & 0xffffu);
            bfr[3][j] = (short)(m.y >> 16);
        }
        #pragma unroll
        for (int mi = 0; mi < 4; mi++){
            bh8 a;
            __builtin_memcpy(&a, wf + (mi*16 + l16)*64 + ks*32 + quad*8, 16);
            #pragma unroll
            for (int p = 0; p < 4; p++)
                accF[mi][p] = mfma16(a, bfr[p], accF[mi][p]);
        }
    }
    {
        float* outF = M.out[seg];
        #pragma unroll
        for (int mi = 0; mi < 4; mi++)
        #pragma unroll
        for (int r = 0; r < 4; r++){
            int o = mi*16 + quad*4 + r;
            size_t pidx = ((size_t)b*64 + o)*HW + pbase;
            f4 rr = rpre[mi*4+r];
            f4 st;
            #pragma unroll
            for (int p = 0; p < 4; p++) st[p] = accF[mi][p][r] + rr[p];
            *(f4*)(outF + pidx) = st;
        }
    }
}

extern "C" void kernel_launch(void* const* d_in, const int* in_sizes, int n_in,
                              void* d_out, int out_size, void* d_ws, size_t ws_size,
                              hipStream_t stream){
    const float* x    = (const float*)d_in[0];
    const float* y    = (const float*)d_in[1];
    const float* ln_w = (const float*)d_in[2];
    const float* ln_b = (const float*)d_in[3];
    const float* temp = (const float*)d_in[4];
    const float* kv_w[2]   = {(const float*)d_in[5],  (const float*)d_in[10]};
    const float* kvdw_w[2] = {(const float*)d_in[6],  (const float*)d_in[11]};
    const float* q_w[2]    = {(const float*)d_in[7],  (const float*)d_in[12]};
    const float* qdw_w[2]  = {(const float*)d_in[8],  (const float*)d_in[13]};
    const float* po_w[2]   = {(const float*)d_in[9],  (const float*)d_in[14]};
    const float* mm_w[2]   = {(const float*)d_in[15], (const float*)d_in[17]};
    const float* mm_b[2]   = {(const float*)d_in[16], (const float*)d_in[18]};

    const size_t HPE = (size_t)BATCH*64*HW;   // elems per 64-ch plane
    u16* PL = (u16*)d_ws;                     // 12 planes
    u16* P[12];
    for (int i = 0; i < 12; i++) P[i] = PL + (size_t)i*HPE;
    float* sums = (float*)(PL + 12*HPE);      // 2 * 2560 f32
    float* lnc  = sums + 5120;                // 768 f32 LN rowsum constants
    u16* warena = (u16*)(lnc + 768);
    // merged gemm arenas: seg0 = kv_w[0](8192) + q_w[1](4096); seg1 = kv_w[1] + q_w[0]
    const int WG[2] = {0, 12288};
    const int WMA[2] = {24576, 40960}, WMB[2] = {32768, 49152};
    const int WEFF[2] = {57344, 73728};

    size_t need = 12*HPE*2 + (5120+768)*4 + 90112*2;
    if (ws_size < need) return;

    SetupArgs S{};
    int nj = 0;
    auto add = [&](const float* s, u16* d, int n, const float* cs){ S.j[nj] = {s, d, n, cs}; nj++; };
    add(kv_w[0], warena + WG[0],        8192, ln_w);
    add(q_w[1],  warena + WG[0] + 8192, 4096, ln_w);
    add(kv_w[1], warena + WG[1],        8192, ln_w);
    add(q_w[0],  warena + WG[1] + 8192, 4096, ln_w);
    for (int br = 0; br < 2; br++){
        add(mm_w[br],        warena + WMA[br],        4096, nullptr);  // W0 -> rows 0-63
        add(mm_w[br]+8192,   warena + WMA[br] + 4096, 4096, nullptr);  // W2 -> rows 64-127
        add(mm_w[br]+4096,   warena + WMB[br],        4096, nullptr);  // W1 -> rows 0-63
        add(mm_w[br]+12288,  warena + WMB[br] + 4096, 4096, nullptr);  // W3 -> rows 64-127
    }
    S.kvw[0] = kv_w[0]; S.kvw[1] = kv_w[1];
    S.qw[0]  = q_w[0];  S.qw[1]  = q_w[1];
    S.lnw = ln_w; S.lnb = ln_b; S.sums = sums; S.lnc = lnc;
    setup_kernel<<<15, 256, 0, stream>>>(S);

    const int GT = NPIX/256;     // 1024 gemm tiles per seg (256 px each)

    // merged LN-GEMM: seg0 x -> P0(k0),P1(v0),P5(q1); seg1 y -> P2(k1),P3(v1),P4(q0)
    GemmMerged GK{};
    GK.in[0] = x; GK.in[1] = y;
    GK.wa[0] = warena + WG[0]; GK.wa[1] = warena + WG[1];
    GK.rs[0] = lnc;        GK.rb[0] = lnc + 192;
    GK.rs[1] = lnc + 384;  GK.rb[1] = lnc + 576;
    GK.out0[0] = P[0]; GK.out1[0] = P[1]; GK.out2[0] = P[5];
    GK.out0[1] = P[2]; GK.out1[1] = P[3]; GK.out2[1] = P[4];
    gemmln_kernel<<<2*GT, 256, 0, stream>>>(GK);

    // depthwise, all 6 planes in one dispatch:
    // br0: P0->P6 (k), P1->P7 (v), P4->P8 (q); br1: P2->P9, P3->P10, P5->P11
    Dw6 D{};
    D.in[0] = P[0];  D.out[0] = P[6];  D.w[0] = kvdw_w[0]; D.choff[0] = 0;
    D.in[1] = P[1];  D.out[1] = P[7];  D.w[1] = kvdw_w[0]; D.choff[1] = 64;
    D.in[2] = P[4];  D.out[2] = P[8];  D.w[2] = qdw_w[0];  D.choff[2] = 0;
    D.in[3] = P[2];  D.out[3] = P[9];  D.w[3] = kvdw_w[1]; D.choff[3] = 0;
    D.in[4] = P[3];  D.out[4] = P[10]; D.w[4] = kvdw_w[1]; D.choff[4] = 64;
    D.in[5] = P[5];  D.out[5] = P[11]; D.w[5] = qdw_w[1];  D.choff[5] = 0;
    dw6_kernel<<<6*8192, 256, 0, stream>>>(D);

    // attention stats both branches
    AttnDual AD{};
    AD.q[0] = P[8];  AD.k[0] = P[6];
    AD.q[1] = P[11]; AD.k[1] = P[9];
    AD.sums = sums;
    attn_part_kernel<<<2*BATCH*8*NSL, 256, 0, stream>>>(AD);

    // softmax + Weff both branches
    WeffDual WD{};
    WD.sums = sums; WD.temp = temp;
    WD.po[0] = po_w[0]; WD.po[1] = po_w[1];
    WD.weff[0] = warena + WEFF[0]; WD.weff[1] = warena + WEFF[1];
    weff_kernel<<<2*BATCH, 64, 0, stream>>>(WD);

    // fused modulation + final both branches
    float* outp = (float*)d_out;
    ModFinal M{};
    M.in[0] = x; M.in[1] = y;
    M.wa[0] = warena + WMA[0]; M.wa[1] = warena + WMA[1];
    M.wb[0] = warena + WMB[0]; M.wb[1] = warena + WMB[1];
    M.b0[0] = mm_b[0];       M.b0[1] = mm_b[1];
    M.b2[0] = mm_b[0] + 128; M.b2[1] = mm_b[1] + 128;
    M.b1[0] = mm_b[0] + 64;  M.b1[1] = mm_b[1] + 64;
    M.b3[0] = mm_b[0] + 192; M.b3[1] = mm_b[1] + 192;
    M.wf[0] = warena + WEFF[0]; M.wf[1] = warena + WEFF[1];
    M.v[0] = P[7]; M.v[1] = P[10];
    M.resid[0] = y; M.resid[1] = x;
    M.out[0] = outp; M.out[1] = outp + HPE;
    modfinal_kernel<<<2*GT, 256, 0, stream>>>(M);
}